// Round 1
// baseline (4425.690 us; speedup 1.0000x reference)
//
#include <hip/hip_runtime.h>
#include <stdint.h>

#define TT 128
#define BB 32
#define HH 512
#define MM 4096            // T*B == S*B
#define VD 32000
#define NBL 128            // persistent LSTM blocks

typedef float f32x4 __attribute__((ext_vector_type(4)));
typedef short s16x8 __attribute__((ext_vector_type(8)));
typedef unsigned long long u64;

__device__ __forceinline__ ushort f2bf(float f){
  uint u = __float_as_uint(f);
  return (ushort)((u + 0x7fffu + ((u >> 16) & 1u)) >> 16);   // RTNE
}
__device__ __forceinline__ float bfl(uint v){ return __uint_as_float(v << 16); }
__device__ __forceinline__ float bfh(uint v){ return __uint_as_float(v & 0xffff0000u); }
__device__ __forceinline__ float bfu(ushort v){ return __uint_as_float(((uint)v) << 16); }

// ---------------- init: zero LSTM state + barrier ----------------
__global__ void k_init(float* cbuf, u64* hbuf, int* cnt){
  int i = blockIdx.x * 256 + threadIdx.x;
  if (i < NBL * BB * 4) cbuf[i] = 0.f;
  if (i < BB * HH / 4) hbuf[i] = 0ull;
  if (i == 0) cnt[0] = 0;
}

// ---------------- f32 -> bf16 convert ----------------
__global__ __launch_bounds__(256) void k_cvt(const float* __restrict__ s, ushort* __restrict__ d, int n4){
  int i = blockIdx.x * 256 + threadIdx.x;
  int st = gridDim.x * 256;
  for (; i < n4; i += st){
    f32x4 v = *(const f32x4*)(s + (size_t)i * 4);
    ushort4 o; o.x = f2bf(v[0]); o.y = f2bf(v[1]); o.z = f2bf(v[2]); o.w = f2bf(v[3]);
    *(ushort4*)(d + (size_t)i * 4) = o;
  }
}

// ---------------- embedding gather -> bf16 ----------------
__global__ __launch_bounds__(128) void k_embed(const int* __restrict__ ids, const float* __restrict__ emb,
                                               ushort* __restrict__ out){
  int row = blockIdx.x, t = threadIdx.x;     // 4096 rows, 128 thr
  int id = ids[row];
  f32x4 v = *(const f32x4*)(emb + (size_t)id * HH + t * 4);
  ushort4 o; o.x = f2bf(v[0]); o.y = f2bf(v[1]); o.z = f2bf(v[2]); o.w = f2bf(v[3]);
  *(ushort4*)(out + (size_t)row * HH + t * 4) = o;
}

// ---------------- build concat weight [512][1024] = [We | Wd] ----------------
__global__ __launch_bounds__(128) void k_concatB(const float* __restrict__ We, const float* __restrict__ Wd,
                                                 ushort* __restrict__ Bc){
  int n = blockIdx.x, t = threadIdx.x;       // 512 rows, 128 thr
  f32x4 a = *(const f32x4*)(We + (size_t)n * HH + t * 4);
  f32x4 b = *(const f32x4*)(Wd + (size_t)n * HH + t * 4);
  ushort4 oa, ob;
  oa.x = f2bf(a[0]); oa.y = f2bf(a[1]); oa.z = f2bf(a[2]); oa.w = f2bf(a[3]);
  ob.x = f2bf(b[0]); ob.y = f2bf(b[1]); ob.z = f2bf(b[2]); ob.w = f2bf(b[3]);
  *(ushort4*)(Bc + (size_t)n * 1024 + t * 4) = oa;
  *(ushort4*)(Bc + (size_t)n * 1024 + 512 + t * 4) = ob;
}
__global__ void k_bsum(const float* a, const float* b, float* o){
  int i = blockIdx.x * 256 + threadIdx.x;
  if (i < HH) o[i] = a[i] + b[i];
}

// ---------------- bf16 MFMA GEMM, C = A[M,K] * B[N,K]^T (+bias)(+tanh) ----------------
// 128x128 tile, BK=32, 4 waves (2x2), 4x4 16x16 frags/wave, global_load_lds width 16.
template<bool BIAS, bool TANH, bool OUTBF>
__global__ __launch_bounds__(256) void k_gemm(const ushort* __restrict__ A, const ushort* __restrict__ Bm,
                                              const float* __restrict__ bias, void* __restrict__ Cout,
                                              int Mtot, int Ntot, int K){
  __shared__ __align__(16) ushort As[128 * 32];
  __shared__ __align__(16) ushort Bs[128 * 32];
  const int tid = threadIdx.x;
  const int m0 = blockIdx.y << 7, n0 = blockIdx.x << 7;
  const int wid = tid >> 6, lane = tid & 63;
  const int wm = wid >> 1, wn = wid & 1;
  const int lr = lane & 15, lk = (lane >> 4) << 3, cr = (lane >> 4) << 2;
  f32x4 acc[4][4];
  for (int i = 0; i < 4; ++i)
    for (int j = 0; j < 4; ++j)
      acc[i][j] = (f32x4){0.f, 0.f, 0.f, 0.f};
  const int c0 = tid, c1 = tid + 256;        // 512 chunks of 16B per 8KB tile
  const size_t ar0 = (size_t)(m0 + (c0 >> 2)) * K + ((c0 & 3) << 3);
  const size_t ar1 = (size_t)(m0 + (c1 >> 2)) * K + ((c1 & 3) << 3);
  const size_t br0 = (size_t)(n0 + (c0 >> 2)) * K + ((c0 & 3) << 3);
  const size_t br1 = (size_t)(n0 + (c1 >> 2)) * K + ((c1 & 3) << 3);
  for (int k0 = 0; k0 < K; k0 += 32){
    __syncthreads();
    __builtin_amdgcn_global_load_lds((const __attribute__((address_space(1))) void*)(A + ar0 + k0),
                                     (__attribute__((address_space(3))) void*)(As + (c0 << 3)), 16, 0, 0);
    __builtin_amdgcn_global_load_lds((const __attribute__((address_space(1))) void*)(A + ar1 + k0),
                                     (__attribute__((address_space(3))) void*)(As + (c1 << 3)), 16, 0, 0);
    __builtin_amdgcn_global_load_lds((const __attribute__((address_space(1))) void*)(Bm + br0 + k0),
                                     (__attribute__((address_space(3))) void*)(Bs + (c0 << 3)), 16, 0, 0);
    __builtin_amdgcn_global_load_lds((const __attribute__((address_space(1))) void*)(Bm + br1 + k0),
                                     (__attribute__((address_space(3))) void*)(Bs + (c1 << 3)), 16, 0, 0);
    __syncthreads();   // drains vmcnt -> staging complete
    s16x8 af[4], bf[4];
    #pragma unroll
    for (int f = 0; f < 4; ++f){
      af[f] = *(const s16x8*)(As + ((wm << 6) + (f << 4) + lr) * 32 + lk);
      bf[f] = *(const s16x8*)(Bs + ((wn << 6) + (f << 4) + lr) * 32 + lk);
    }
    #pragma unroll
    for (int fm = 0; fm < 4; ++fm)
      #pragma unroll
      for (int fn = 0; fn < 4; ++fn)
        acc[fm][fn] = __builtin_amdgcn_mfma_f32_16x16x32_bf16(af[fm], bf[fn], acc[fm][fn], 0, 0, 0);
  }
  #pragma unroll
  for (int fn = 0; fn < 4; ++fn){
    const int col = n0 + (wn << 6) + (fn << 4) + lr;
    const float bv = BIAS ? bias[col] : 0.f;
    #pragma unroll
    for (int fm = 0; fm < 4; ++fm){
      const int rw = m0 + (wm << 6) + (fm << 4) + cr;
      #pragma unroll
      for (int r = 0; r < 4; ++r){
        float v = acc[fm][fn][r] + bv;
        if (TANH) v = tanhf(v);
        const size_t off = (size_t)(rw + r) * Ntot + col;
        if (OUTBF) ((ushort*)Cout)[off] = f2bf(v);
        else       ((float*)Cout)[off] = v;
      }
    }
  }
}

// ---------------- persistent LSTM (encoder then decoder), 128 blocks x 512 thr ----------------
// Block bk owns h-slice j in [bk*4, bk*4+4) (16 Whh rows). h exchanged via LLC with
// agent-scope atomics (no L2 fences -> Whh stays L2-cached). Barrier = monotonic counter.
__global__ __launch_bounds__(512) void k_lstm(const float* __restrict__ GinE, const float* __restrict__ GinD,
                                              const float* __restrict__ WhhE, const float* __restrict__ WhhD,
                                              u64* hbuf, float* cbuf, int* cnt,
                                              ushort* encO, ushort* decO, ushort* Ac){
  __shared__ __align__(16) ushort h_lds[32 * 512];   // [b][k] bf16, 32 KB
  __shared__ float gates[2 * 16 * 32];               // [khalf][jg][b]
  const int tid = threadIdx.x;
  const int bk = blockIdx.x;
  const int j0 = bk << 2;
  const int kh = tid >> 8;          // k-half 0/1
  const int t2 = tid & 255;
  const int b = t2 & 31;
  const int jg = t2 >> 5;           // 0..7
  const int row0 = ((jg >> 2) << 9) + j0 + (jg & 3);           // gates 0..1
  const int row1 = (((jg + 8) >> 2) << 9) + j0 + ((jg + 8) & 3); // gates 2..3
  const int kb = kh << 8;
  int target = 0;
  for (int ph = 0; ph < 2; ++ph){
    const float* Gin = ph ? GinD : GinE;
    const float* Whh = ph ? WhhD : WhhE;
    ushort* hall = ph ? decO : encO;
    for (int t = 0; t < TT; ++t){
      // ---- load h (LLC-coherent) into LDS, linear u64 mapping ----
      #pragma unroll
      for (int j = 0; j < 8; ++j){
        int u = tid + (j << 9);     // 4096 u64 = 32KB
        u64 v = __hip_atomic_load(hbuf + u, __ATOMIC_RELAXED, __HIP_MEMORY_SCOPE_AGENT);
        *(u64*)(h_lds + (u << 2)) = v;
      }
      // ---- prefetch Gin for combine phase (hides HBM latency under dot phase) ----
      float pgi = 0.f, pgf = 0.f, pgg = 0.f, pgo = 0.f;
      if (tid < 128){
        const float* gp = Gin + ((size_t)(t << 5) + (tid & 31)) * 2048 + j0 + (tid >> 5);
        pgi = gp[0]; pgf = gp[512]; pgg = gp[1024]; pgo = gp[1536];
      }
      __syncthreads();
      // ---- recurrent dots: 2 rows x 256-long half-K per thread ----
      const float* w0 = Whh + ((size_t)row0 << 9) + kb;
      const float* w1 = Whh + ((size_t)row1 << 9) + kb;
      const ushort* hrow = h_lds + (b << 9) + kb;
      float a0 = 0.f, a1 = 0.f;
      #pragma unroll 8
      for (int k = 0; k < 256; k += 4){
        const int kk = (k + (b << 2)) & 255;    // per-b rotation: LDS bank spread
        ushort4 hv = *(const ushort4*)(hrow + kk);
        f32x4 wv0 = *(const f32x4*)(w0 + kk);
        f32x4 wv1 = *(const f32x4*)(w1 + kk);
        const float h0 = bfu(hv.x), h1 = bfu(hv.y), h2 = bfu(hv.z), h3 = bfu(hv.w);
        a0 += h0 * wv0[0] + h1 * wv0[1] + h2 * wv0[2] + h3 * wv0[3];
        a1 += h0 * wv1[0] + h1 * wv1[1] + h2 * wv1[2] + h3 * wv1[3];
      }
      gates[(kh << 9) + (jg << 5) + b] = a0;
      gates[(kh << 9) + ((jg + 8) << 5) + b] = a1;
      __syncthreads();
      // ---- gate combine + state update (threads 0..127 = (b, jl)) ----
      if (tid < 128){
        const int bb = tid & 31, jl = tid >> 5;
        float gi = gates[((jl     ) << 5) + bb] + gates[512 + ((jl     ) << 5) + bb] + pgi;
        float gf = gates[((4 + jl ) << 5) + bb] + gates[512 + ((4 + jl ) << 5) + bb] + pgf;
        float gg = gates[((8 + jl ) << 5) + bb] + gates[512 + ((8 + jl ) << 5) + bb] + pgg;
        float go = gates[((12 + jl) << 5) + bb] + gates[512 + ((12 + jl) << 5) + bb] + pgo;
        const float si = 1.f / (1.f + __expf(-gi));
        const float sf = 1.f / (1.f + __expf(-gf));
        const float so = 1.f / (1.f + __expf(-go));
        float* cp = cbuf + (((bk << 5) + bb) << 2) + jl;   // block-private, L2-cached
        const float c = sf * cp[0] + si * tanhf(gg);
        cp[0] = c;
        const ushort hb = f2bf(so * tanhf(c));
        // agent-scope stores: LLC write-through, no cross-XCD dirty-line aliasing
        __hip_atomic_store((ushort*)hbuf + (bb << 9) + j0 + jl, hb,
                           __ATOMIC_RELAXED, __HIP_MEMORY_SCOPE_AGENT);
        __hip_atomic_store(hall + (((size_t)(t << 5) + bb) << 9) + j0 + jl, hb,
                           __ATOMIC_RELAXED, __HIP_MEMORY_SCOPE_AGENT);
        if (ph)
          __hip_atomic_store(Ac + (((size_t)(t << 5) + bb) << 10) + 512 + j0 + jl, hb,
                             __ATOMIC_RELAXED, __HIP_MEMORY_SCOPE_AGENT);
      }
      // ---- device barrier (syncthreads drains vmcnt before arrive) ----
      target += NBL;
      __syncthreads();
      if (tid == 0){
        __hip_atomic_fetch_add(cnt, 1, __ATOMIC_RELAXED, __HIP_MEMORY_SCOPE_AGENT);
        while (__hip_atomic_load(cnt, __ATOMIC_RELAXED, __HIP_MEMORY_SCOPE_AGENT) < target)
          __builtin_amdgcn_s_sleep(2);
      }
      __syncthreads();
    }
  }
}

// ---------------- fused attention: scores -> softmax -> ctx, per (b, s-tile of 16) ----------------
__global__ __launch_bounds__(256) void k_attn(const ushort* __restrict__ enc, const ushort* __restrict__ dec,
                                              ushort* __restrict__ Ac){
  __shared__ __align__(16) float dec_lds[16 * 512];  // 32 KB
  __shared__ __align__(16) float P[16 * 128];        // 8 KB
  const int tid = threadIdx.x;
  const int b = blockIdx.x & 31, st = blockIdx.x >> 5;
  const int s0 = st << 4;
  // stage 16 decoder rows (f32) into LDS
  for (int j = 0; j < 4; ++j){
    int e8 = tid + (j << 8);                 // 1024 chunks of 8 bf16
    int sl = e8 >> 6, k = (e8 & 63) << 3;
    uint4 v = *(const uint4*)(dec + ((size_t)((s0 + sl) * 32 + b) << 9) + k);
    float* dst = dec_lds + sl * 512 + k;
    dst[0] = bfl(v.x); dst[1] = bfh(v.x); dst[2] = bfl(v.y); dst[3] = bfh(v.y);
    dst[4] = bfl(v.z); dst[5] = bfh(v.z); dst[6] = bfl(v.w); dst[7] = bfh(v.w);
  }
  __syncthreads();
  // scores[s, t] = <dec[s], enc[t]>
  {
    const int tl = tid & 127, sh = tid >> 7;
    const ushort* erow = enc + ((size_t)(tl * 32 + b) << 9);
    float acc8[8] = {0.f, 0.f, 0.f, 0.f, 0.f, 0.f, 0.f, 0.f};
    for (int k = 0; k < 512; k += 8){
      uint4 v = *(const uint4*)(erow + k);
      const float e0 = bfl(v.x), e1 = bfh(v.x), e2 = bfl(v.y), e3 = bfh(v.y);
      const float e4 = bfl(v.z), e5 = bfh(v.z), e6 = bfl(v.w), e7 = bfh(v.w);
      const float* dl = dec_lds + (sh << 3) * 512 + k;
      #pragma unroll
      for (int i = 0; i < 8; ++i){
        f32x4 d0 = *(const f32x4*)(dl + i * 512);
        f32x4 d1 = *(const f32x4*)(dl + i * 512 + 4);
        acc8[i] += d0[0]*e0 + d0[1]*e1 + d0[2]*e2 + d0[3]*e3
                 + d1[0]*e4 + d1[1]*e5 + d1[2]*e6 + d1[3]*e7;
      }
    }
    #pragma unroll
    for (int i = 0; i < 8; ++i) P[((sh << 3) + i) * 128 + tl] = acc8[i];
  }
  __syncthreads();
  // softmax over t (128), one row per 16 lanes
  {
    const int r = tid >> 4, i = tid & 15;
    float* prow = P + r * 128 + (i << 3);
    float v[8], m = -1e30f;
    #pragma unroll
    for (int j = 0; j < 8; ++j){ v[j] = prow[j]; m = fmaxf(m, v[j]); }
    #pragma unroll
    for (int off = 1; off < 16; off <<= 1) m = fmaxf(m, __shfl_xor(m, off));
    float l = 0.f;
    #pragma unroll
    for (int j = 0; j < 8; ++j){ v[j] = __expf(v[j] - m); l += v[j]; }
    #pragma unroll
    for (int off = 1; off < 16; off <<= 1) l += __shfl_xor(l, off);
    const float inv = 1.f / l;
    #pragma unroll
    for (int j = 0; j < 8; ++j) prow[j] = v[j] * inv;
  }
  __syncthreads();
  // ctx[s, h] = sum_t P[s,t] * enc[t, h]; write bf16 into Ac[:, 0:512]
  {
    const int h0 = tid << 1;
    float acc[16][2];
    #pragma unroll
    for (int sl = 0; sl < 16; ++sl){ acc[sl][0] = 0.f; acc[sl][1] = 0.f; }
    const ushort* ecol = enc + ((size_t)b << 9) + h0;
    for (int t = 0; t < 128; ++t){
      uint v = *(const uint*)(ecol + (size_t)t * 16384);
      const float e0 = bfl(v), e1 = bfh(v);
      #pragma unroll
      for (int sl = 0; sl < 16; ++sl){
        const float p = P[sl * 128 + t];
        acc[sl][0] += p * e0; acc[sl][1] += p * e1;
      }
    }
    #pragma unroll
    for (int sl = 0; sl < 16; ++sl){
      const int m = (s0 + sl) * 32 + b;
      uint u = ((uint)f2bf(acc[sl][1]) << 16) | (uint)f2bf(acc[sl][0]);
      *(uint*)(Ac + (size_t)m * 1024 + h0) = u;
    }
  }
}

// ---------------- per-row online logsumexp over 32000 ----------------
__global__ __launch_bounds__(256) void k_lse(const float* __restrict__ out, float* __restrict__ lse){
  const int row = blockIdx.x, tid = threadIdx.x;
  const float* p = out + (size_t)row * VD;
  float m = -1e30f, l = 0.f;
  for (int i4 = tid; i4 < VD / 4; i4 += 256){
    f32x4 v = *(const f32x4*)(p + ((size_t)i4 << 2));
    float m4 = fmaxf(fmaxf(v[0], v[1]), fmaxf(v[2], v[3]));
    float s4 = __expf(v[0] - m4) + __expf(v[1] - m4) + __expf(v[2] - m4) + __expf(v[3] - m4);
    if (m4 > m){ l = l * __expf(m - m4) + s4; m = m4; }
    else l += s4 * __expf(m4 - m);
  }
  #pragma unroll
  for (int off = 32; off; off >>= 1){
    float m2 = __shfl_xor(m, off), l2 = __shfl_xor(l, off);
    float nm = fmaxf(m, m2);
    l = l * __expf(m - nm) + l2 * __expf(m2 - nm);
    m = nm;
  }
  __shared__ float rm[4], rl[4];
  if ((tid & 63) == 0){ rm[tid >> 6] = m; rl[tid >> 6] = l; }
  __syncthreads();
  if (tid == 0){
    float M = rm[0], L = rl[0];
    for (int w = 1; w < 4; ++w){
      float nm = fmaxf(M, rm[w]);
      L = L * __expf(M - nm) + rl[w] * __expf(rm[w] - nm);
      M = nm;
    }
    lse[row] = M + __logf(L);
  }
}

// ---------------- in-place subtract lse ----------------
__global__ __launch_bounds__(256) void k_sub(float* __restrict__ out, const float* __restrict__ lse){
  const int row = blockIdx.x;
  const float s = lse[row];
  float* p = out + (size_t)row * VD;
  for (int i4 = threadIdx.x; i4 < VD / 4; i4 += 256){
    f32x4 v = *(const f32x4*)(p + ((size_t)i4 << 2));
    v[0] -= s; v[1] -= s; v[2] -= s; v[3] -= s;
    *(f32x4*)(p + ((size_t)i4 << 2)) = v;
  }
}

extern "C" void kernel_launch(void* const* d_in, const int* in_sizes, int n_in,
                              void* d_out, int out_size, void* d_ws, size_t ws_size,
                              hipStream_t stream){
  const int*   enc_in  = (const int*)d_in[0];
  const int*   dec_in  = (const int*)d_in[1];
  const float* enc_emb = (const float*)d_in[2];
  const float* dec_emb = (const float*)d_in[3];
  const float* WihE    = (const float*)d_in[4];
  const float* WhhE    = (const float*)d_in[5];
  const float* WihD    = (const float*)d_in[6];
  const float* WhhD    = (const float*)d_in[7];
  const float* We      = (const float*)d_in[8];
  const float* be      = (const float*)d_in[9];
  const float* Wd      = (const float*)d_in[10];
  const float* bd      = (const float*)d_in[11];
  const float* outW    = (const float*)d_in[12];
  const float* outb    = (const float*)d_in[13];
  float* out = (float*)d_out;

  char* ws = (char*)d_ws;
  size_t off = 0;
  auto alloc = [&](size_t bytes){ void* p = ws + off; off += (bytes + 255) & ~(size_t)255; return p; };
  ushort* xe    = (ushort*)alloc((size_t)MM * HH * 2);
  ushort* xd    = (ushort*)alloc((size_t)MM * HH * 2);
  ushort* WihEb = (ushort*)alloc((size_t)2048 * 512 * 2);
  ushort* WihDb = (ushort*)alloc((size_t)2048 * 512 * 2);
  ushort* Bc    = (ushort*)alloc((size_t)512 * 1024 * 2);
  float*  bsum  = (float*)alloc(512 * 4);
  ushort* outWb = (ushort*)alloc((size_t)VD * HH * 2);
  ushort* encO  = (ushort*)alloc((size_t)MM * HH * 2);
  ushort* decO  = (ushort*)alloc((size_t)MM * HH * 2);
  u64*    hbuf  = (u64*)alloc(BB * HH * 2);
  float*  cbuf  = (float*)alloc(NBL * BB * 4 * 4);
  int*    cnt   = (int*)alloc(256);
  ushort* Ac    = (ushort*)alloc((size_t)MM * 1024 * 2);
  ushort* hid   = (ushort*)alloc((size_t)MM * HH * 2);
  float*  lse   = (float*)alloc(MM * 4);
  // Gin buffers (67 MB) live in d_out-as-scratch: dead before logits GEMM writes d_out.
  float* GinE = out;
  float* GinD = out + (size_t)MM * 2048;

  k_init<<<dim3(64), dim3(256), 0, stream>>>(cbuf, hbuf, cnt);
  k_cvt<<<dim3(1024), dim3(256), 0, stream>>>(WihE, WihEb, 2048 * 512 / 4);
  k_cvt<<<dim3(1024), dim3(256), 0, stream>>>(WihD, WihDb, 2048 * 512 / 4);
  k_cvt<<<dim3(2048), dim3(256), 0, stream>>>(outW, outWb, VD * HH / 4);
  k_concatB<<<dim3(512), dim3(128), 0, stream>>>(We, Wd, Bc);
  k_bsum<<<dim3(2), dim3(256), 0, stream>>>(be, bd, bsum);
  k_embed<<<dim3(MM), dim3(128), 0, stream>>>(enc_in, enc_emb, xe);
  k_embed<<<dim3(MM), dim3(128), 0, stream>>>(dec_in, dec_emb, xd);
  // input projections: Gin = x @ Wih^T   [4096,512]x[2048,512]^T
  k_gemm<false, false, false><<<dim3(16, 32), dim3(256), 0, stream>>>(xe, WihEb, (const float*)nullptr, GinE, MM, 2048, 512);
  k_gemm<false, false, false><<<dim3(16, 32), dim3(256), 0, stream>>>(xd, WihDb, (const float*)nullptr, GinD, MM, 2048, 512);
  // both LSTMs (persistent, 256 internal device barriers)
  k_lstm<<<dim3(NBL), dim3(512), 0, stream>>>(GinE, GinD, WhhE, WhhD, hbuf, cbuf, cnt, encO, decO, Ac);
  // attention -> ctx into Ac[:, 0:512] (dec h already in Ac[:, 512:1024])
  k_attn<<<dim3(256), dim3(256), 0, stream>>>(encO, decO, Ac);
  // hidden = tanh([ctx|dec] @ [We|Wd]^T + (be+bd))   K=1024 -> bf16
  k_gemm<true, true, true><<<dim3(4, 32), dim3(256), 0, stream>>>(Ac, Bc, bsum, hid, MM, 512, 1024);
  // logits = hidden @ outW^T + out_b -> d_out (f32)
  k_gemm<true, false, false><<<dim3(250, 32), dim3(256), 0, stream>>>(hid, outWb, outb, out, MM, VD, 512);
  // log-softmax
  k_lse<<<dim3(MM), dim3(256), 0, stream>>>(out, lse);
  k_sub<<<dim3(MM), dim3(256), 0, stream>>>(out, lse);
}

// Round 2
// 3781.037 us; speedup vs baseline: 1.1705x; 1.1705x over previous
//
#include <hip/hip_runtime.h>
#include <stdint.h>

#define TT 128
#define BB 32
#define HH 512
#define MM 4096            // T*B == S*B
#define VD 32000
#define NLB 32             // persistent LSTM blocks (one j-slice of 16 h-units each)

typedef float f32x4 __attribute__((ext_vector_type(4)));
typedef short s16x8 __attribute__((ext_vector_type(8)));
typedef unsigned long long u64;

__device__ __forceinline__ ushort f2bf(float f){
  uint u = __float_as_uint(f);
  return (ushort)((u + 0x7fffu + ((u >> 16) & 1u)) >> 16);   // RTNE
}
__device__ __forceinline__ float bfl(uint v){ return __uint_as_float(v << 16); }
__device__ __forceinline__ float bfh(uint v){ return __uint_as_float(v & 0xffff0000u); }
__device__ __forceinline__ float bfu(ushort v){ return __uint_as_float(((uint)v) << 16); }

// ---------------- init: zero h double-buffer + tags ----------------
__global__ void k_init(u64* hbuf, uint* tags){
  int i = blockIdx.x * 256 + threadIdx.x;
  if (i < 8192) hbuf[i] = 0ull;          // 2 x 32 x 512 bf16 = 64 KB
  if (i < NLB) tags[i] = 0u;
}

// ---------------- f32 -> bf16 convert ----------------
__global__ __launch_bounds__(256) void k_cvt(const float* __restrict__ s, ushort* __restrict__ d, int n4){
  int i = blockIdx.x * 256 + threadIdx.x;
  int st = gridDim.x * 256;
  for (; i < n4; i += st){
    f32x4 v = *(const f32x4*)(s + (size_t)i * 4);
    ushort4 o; o.x = f2bf(v[0]); o.y = f2bf(v[1]); o.z = f2bf(v[2]); o.w = f2bf(v[3]);
    *(ushort4*)(d + (size_t)i * 4) = o;
  }
}

// ---------------- embedding gather -> bf16 ----------------
__global__ __launch_bounds__(128) void k_embed(const int* __restrict__ ids, const float* __restrict__ emb,
                                               ushort* __restrict__ out){
  int row = blockIdx.x, t = threadIdx.x;     // 4096 rows, 128 thr
  int id = ids[row];
  f32x4 v = *(const f32x4*)(emb + (size_t)id * HH + t * 4);
  ushort4 o; o.x = f2bf(v[0]); o.y = f2bf(v[1]); o.z = f2bf(v[2]); o.w = f2bf(v[3]);
  *(ushort4*)(out + (size_t)row * HH + t * 4) = o;
}

// ---------------- build concat weight [512][1024] = [We | Wd] ----------------
__global__ __launch_bounds__(128) void k_concatB(const float* __restrict__ We, const float* __restrict__ Wd,
                                                 ushort* __restrict__ Bc){
  int n = blockIdx.x, t = threadIdx.x;       // 512 rows, 128 thr
  f32x4 a = *(const f32x4*)(We + (size_t)n * HH + t * 4);
  f32x4 b = *(const f32x4*)(Wd + (size_t)n * HH + t * 4);
  ushort4 oa, ob;
  oa.x = f2bf(a[0]); oa.y = f2bf(a[1]); oa.z = f2bf(a[2]); oa.w = f2bf(a[3]);
  ob.x = f2bf(b[0]); ob.y = f2bf(b[1]); ob.z = f2bf(b[2]); ob.w = f2bf(b[3]);
  *(ushort4*)(Bc + (size_t)n * 1024 + t * 4) = oa;
  *(ushort4*)(Bc + (size_t)n * 1024 + 512 + t * 4) = ob;
}
__global__ void k_bsum(const float* a, const float* b, float* o){
  int i = blockIdx.x * 256 + threadIdx.x;
  if (i < HH) o[i] = a[i] + b[i];
}

// ---------------- bf16 MFMA GEMM, C = A[M,K] * B[N,K]^T (+bias)(+tanh) ----------------
template<bool BIAS, bool TANH, bool OUTBF>
__global__ __launch_bounds__(256) void k_gemm(const ushort* __restrict__ A, const ushort* __restrict__ Bm,
                                              const float* __restrict__ bias, void* __restrict__ Cout,
                                              int Mtot, int Ntot, int K){
  __shared__ __align__(16) ushort As[128 * 32];
  __shared__ __align__(16) ushort Bs[128 * 32];
  const int tid = threadIdx.x;
  const int m0 = blockIdx.y << 7, n0 = blockIdx.x << 7;
  const int wid = tid >> 6, lane = tid & 63;
  const int wm = wid >> 1, wn = wid & 1;
  const int lr = lane & 15, lk = (lane >> 4) << 3, cr = (lane >> 4) << 2;
  f32x4 acc[4][4];
  for (int i = 0; i < 4; ++i)
    for (int j = 0; j < 4; ++j)
      acc[i][j] = (f32x4){0.f, 0.f, 0.f, 0.f};
  const int c0 = tid, c1 = tid + 256;
  const size_t ar0 = (size_t)(m0 + (c0 >> 2)) * K + ((c0 & 3) << 3);
  const size_t ar1 = (size_t)(m0 + (c1 >> 2)) * K + ((c1 & 3) << 3);
  const size_t br0 = (size_t)(n0 + (c0 >> 2)) * K + ((c0 & 3) << 3);
  const size_t br1 = (size_t)(n0 + (c1 >> 2)) * K + ((c1 & 3) << 3);
  for (int k0 = 0; k0 < K; k0 += 32){
    __syncthreads();
    __builtin_amdgcn_global_load_lds((const __attribute__((address_space(1))) void*)(A + ar0 + k0),
                                     (__attribute__((address_space(3))) void*)(As + (c0 << 3)), 16, 0, 0);
    __builtin_amdgcn_global_load_lds((const __attribute__((address_space(1))) void*)(A + ar1 + k0),
                                     (__attribute__((address_space(3))) void*)(As + (c1 << 3)), 16, 0, 0);
    __builtin_amdgcn_global_load_lds((const __attribute__((address_space(1))) void*)(Bm + br0 + k0),
                                     (__attribute__((address_space(3))) void*)(Bs + (c0 << 3)), 16, 0, 0);
    __builtin_amdgcn_global_load_lds((const __attribute__((address_space(1))) void*)(Bm + br1 + k0),
                                     (__attribute__((address_space(3))) void*)(Bs + (c1 << 3)), 16, 0, 0);
    __syncthreads();
    s16x8 af[4], bf[4];
    #pragma unroll
    for (int f = 0; f < 4; ++f){
      af[f] = *(const s16x8*)(As + ((wm << 6) + (f << 4) + lr) * 32 + lk);
      bf[f] = *(const s16x8*)(Bs + ((wn << 6) + (f << 4) + lr) * 32 + lk);
    }
    #pragma unroll
    for (int fm = 0; fm < 4; ++fm)
      #pragma unroll
      for (int fn = 0; fn < 4; ++fn)
        acc[fm][fn] = __builtin_amdgcn_mfma_f32_16x16x32_bf16(af[fm], bf[fn], acc[fm][fn], 0, 0, 0);
  }
  #pragma unroll
  for (int fn = 0; fn < 4; ++fn){
    const int col = n0 + (wn << 6) + (fn << 4) + lr;
    const float bv = BIAS ? bias[col] : 0.f;
    #pragma unroll
    for (int fm = 0; fm < 4; ++fm){
      const int rw = m0 + (wm << 6) + (fm << 4) + cr;
      #pragma unroll
      for (int r = 0; r < 4; ++r){
        float v = acc[fm][fn][r] + bv;
        if (TANH) v = tanhf(v);
        const size_t off = (size_t)(rw + r) * Ntot + col;
        if (OUTBF) ((ushort*)Cout)[off] = f2bf(v);
        else       ((float*)Cout)[off] = v;
      }
    }
  }
}

// ---------------- persistent LSTM: 32 blocks x 512 thr, MFMA recurrence ----------------
// Block bk owns h-units J = [bk*16, bk*16+16). Wave w = (m = w&1 batch-half, g = w>>1 gate):
// computes gate g for 16 batches x 16 j via 16x16x32 MFMA over K=512, with Whh fragments
// (bf16 hi + bf16 residual lo -> ~f32 weight precision) persistent in VGPRs.
// h exchanged through LLC (agent-scope), double-buffered by step parity; per-wave
// vmcnt(0) drain + per-block counter add; poll waits all 32 counters >= 8*s.
__global__ __launch_bounds__(512) void k_lstm(const float* __restrict__ GinE, const float* __restrict__ GinD,
                                              const float* __restrict__ WhhE, const float* __restrict__ WhhD,
                                              u64* __restrict__ hbuf, uint* __restrict__ tags,
                                              ushort* __restrict__ encO, ushort* __restrict__ decO,
                                              ushort* __restrict__ Ac){
  __shared__ float gbuf[2048];              // [g][b][j] f32, 8 KB
  const int tid = threadIdx.x;
  const int bk = blockIdx.x;
  const int J0 = bk << 4;
  const int w = tid >> 6, lane = tid & 63;
  const int m = w & 1, g = w >> 1;
  const int lr = lane & 15, lg = lane >> 4;
  const int cb = tid >> 4, cj = tid & 15;   // combine mapping: one (batch, j) per thread

  float c_reg = 0.f;                        // cell state lives in a register for all 256 steps
  s16x8 bhi[16], blo[16];                   // Whh fragments, persistent in VGPRs
  float gin0, gin1, gin2, gin3;
  ushort* hb16 = (ushort*)hbuf;

  { // prologue: Gin for s=0
    const float* gp = GinE + (size_t)cb * 2048 + J0 + cj;
    gin0 = gp[0]; gin1 = gp[512]; gin2 = gp[1024]; gin3 = gp[1536];
  }

  for (int s = 0; s < 256; ++s){
    const int ph = s >> 7, t = s & 127;
    if (t == 0){                            // (re)load weight fragments at phase start
      const float* Whh = ph ? WhhD : WhhE;
      const float* wr = Whh + (size_t)(g * 512 + J0 + lr) * 512 + (lg << 3);
      #pragma unroll
      for (int ks = 0; ks < 16; ++ks){
        f32x4 w0 = *(const f32x4*)(wr + ks * 32);
        f32x4 w1 = *(const f32x4*)(wr + ks * 32 + 4);
        s16x8 h8, l8;
        #pragma unroll
        for (int e = 0; e < 4; ++e){
          ushort hv = f2bf(w0[e]); h8[e] = (short)hv; l8[e] = (short)f2bf(w0[e] - bfu(hv));
          ushort hv2 = f2bf(w1[e]); h8[4 + e] = (short)hv2; l8[4 + e] = (short)f2bf(w1[e] - bfu(hv2));
        }
        bhi[ks] = h8; blo[ks] = l8;
      }
    }
    if (s > 0){                             // wait: all blocks published h(s)
      const uint sv = (uint)(s << 3);       // 8 wave-signals per block per step
      for (;;){
        uint v = __hip_atomic_load(tags + (lane & 31), __ATOMIC_RELAXED, __HIP_MEMORY_SCOPE_AGENT);
        if (__all(v >= sv)) break;
        __builtin_amdgcn_s_sleep(1);
      }
      asm volatile("" ::: "memory");        // no hoisting of h loads above the poll
    }
    // ---- A-fragments of h(s) straight from LLC, then split-bf16 MFMA ----
    f32x4 acc = {0.f, 0.f, 0.f, 0.f};
    const u64* hp = hbuf + ((size_t)(s & 1) << 12) + ((m * 16 + lr) << 7) + (lg << 1);
    #pragma unroll
    for (int kb = 0; kb < 4; ++kb){
      u64 av[8];
      #pragma unroll
      for (int q = 0; q < 4; ++q){
        av[2 * q]     = __hip_atomic_load(hp + (kb * 4 + q) * 8,     __ATOMIC_RELAXED, __HIP_MEMORY_SCOPE_AGENT);
        av[2 * q + 1] = __hip_atomic_load(hp + (kb * 4 + q) * 8 + 1, __ATOMIC_RELAXED, __HIP_MEMORY_SCOPE_AGENT);
      }
      #pragma unroll
      for (int q = 0; q < 4; ++q){
        union { u64 q2[2]; s16x8 v; } u;
        u.q2[0] = av[2 * q]; u.q2[1] = av[2 * q + 1];
        acc = __builtin_amdgcn_mfma_f32_16x16x32_bf16(u.v, bhi[kb * 4 + q], acc, 0, 0, 0);
        acc = __builtin_amdgcn_mfma_f32_16x16x32_bf16(u.v, blo[kb * 4 + q], acc, 0, 0, 0);
      }
    }
    // D-frag: j = lane&15, b = m*16 + (lane>>4)*4 + r  -> gbuf[g][b][j]
    #pragma unroll
    for (int r = 0; r < 4; ++r)
      gbuf[g * 512 + (m * 16 + lg * 4 + r) * 16 + lr] = acc[r];
    __syncthreads();
    // ---- gate combine + state update: thread = (cb, cj) ----
    const float zi = gbuf[tid]        + gin0;
    const float zf = gbuf[512 + tid]  + gin1;
    const float zg = gbuf[1024 + tid] + gin2;
    const float zo = gbuf[1536 + tid] + gin3;
    const float si = 1.f / (1.f + __expf(-zi));
    const float sf = 1.f / (1.f + __expf(-zf));
    const float so = 1.f / (1.f + __expf(-zo));
    c_reg = sf * c_reg + si * tanhf(zg);
    const ushort hb = f2bf(so * tanhf(c_reg));
    __hip_atomic_store(hb16 + (((s + 1) & 1) << 14) + (cb << 9) + J0 + cj, hb,
                       __ATOMIC_RELAXED, __HIP_MEMORY_SCOPE_AGENT);
    ushort* hall = ph ? decO : encO;
    __hip_atomic_store(hall + ((size_t)(t * 32 + cb) << 9) + J0 + cj, hb,
                       __ATOMIC_RELAXED, __HIP_MEMORY_SCOPE_AGENT);
    if (ph)
      __hip_atomic_store(Ac + ((size_t)(t * 32 + cb) << 10) + 512 + J0 + cj, hb,
                         __ATOMIC_RELAXED, __HIP_MEMORY_SCOPE_AGENT);
    // ---- drain own stores (LLC-visible), then signal; no intra-block barrier needed:
    // poll(s+1) implies all 8 waves finished combine reads -> gbuf reuse is safe.
    asm volatile("s_waitcnt vmcnt(0)" ::: "memory");
    if (lane == 0)
      __hip_atomic_fetch_add(tags + bk, 1u, __ATOMIC_RELAXED, __HIP_MEMORY_SCOPE_AGENT);
    if (s < 255){                           // prefetch Gin(s+1) under next poll
      const int s2 = s + 1, t2 = s2 & 127;
      const float* G2 = (s2 >> 7) ? GinD : GinE;
      const float* gp = G2 + (size_t)(t2 * 32 + cb) * 2048 + J0 + cj;
      gin0 = gp[0]; gin1 = gp[512]; gin2 = gp[1024]; gin3 = gp[1536];
    }
  }
}

// ---------------- fused attention: scores -> softmax -> ctx, per (b, s-tile of 16) ----------------
__global__ __launch_bounds__(256) void k_attn(const ushort* __restrict__ enc, const ushort* __restrict__ dec,
                                              ushort* __restrict__ Ac){
  __shared__ __align__(16) float dec_lds[16 * 512];
  __shared__ __align__(16) float P[16 * 128];
  const int tid = threadIdx.x;
  const int b = blockIdx.x & 31, st = blockIdx.x >> 5;
  const int s0 = st << 4;
  for (int j = 0; j < 4; ++j){
    int e8 = tid + (j << 8);
    int sl = e8 >> 6, k = (e8 & 63) << 3;
    uint4 v = *(const uint4*)(dec + ((size_t)((s0 + sl) * 32 + b) << 9) + k);
    float* dst = dec_lds + sl * 512 + k;
    dst[0] = bfl(v.x); dst[1] = bfh(v.x); dst[2] = bfl(v.y); dst[3] = bfh(v.y);
    dst[4] = bfl(v.z); dst[5] = bfh(v.z); dst[6] = bfl(v.w); dst[7] = bfh(v.w);
  }
  __syncthreads();
  {
    const int tl = tid & 127, sh = tid >> 7;
    const ushort* erow = enc + ((size_t)(tl * 32 + b) << 9);
    float acc8[8] = {0.f, 0.f, 0.f, 0.f, 0.f, 0.f, 0.f, 0.f};
    for (int k = 0; k < 512; k += 8){
      uint4 v = *(const uint4*)(erow + k);
      const float e0 = bfl(v.x), e1 = bfh(v.x), e2 = bfl(v.y), e3 = bfh(v.y);
      const float e4 = bfl(v.z), e5 = bfh(v.z), e6 = bfl(v.w), e7 = bfh(v.w);
      const float* dl = dec_lds + (sh << 3) * 512 + k;
      #pragma unroll
      for (int i = 0; i < 8; ++i){
        f32x4 d0 = *(const f32x4*)(dl + i * 512);
        f32x4 d1 = *(const f32x4*)(dl + i * 512 + 4);
        acc8[i] += d0[0]*e0 + d0[1]*e1 + d0[2]*e2 + d0[3]*e3
                 + d1[0]*e4 + d1[1]*e5 + d1[2]*e6 + d1[3]*e7;
      }
    }
    #pragma unroll
    for (int i = 0; i < 8; ++i) P[((sh << 3) + i) * 128 + tl] = acc8[i];
  }
  __syncthreads();
  {
    const int r = tid >> 4, i = tid & 15;
    float* prow = P + r * 128 + (i << 3);
    float v[8], mx = -1e30f;
    #pragma unroll
    for (int j = 0; j < 8; ++j){ v[j] = prow[j]; mx = fmaxf(mx, v[j]); }
    #pragma unroll
    for (int off = 1; off < 16; off <<= 1) mx = fmaxf(mx, __shfl_xor(mx, off));
    float l = 0.f;
    #pragma unroll
    for (int j = 0; j < 8; ++j){ v[j] = __expf(v[j] - mx); l += v[j]; }
    #pragma unroll
    for (int off = 1; off < 16; off <<= 1) l += __shfl_xor(l, off);
    const float inv = 1.f / l;
    #pragma unroll
    for (int j = 0; j < 8; ++j) prow[j] = v[j] * inv;
  }
  __syncthreads();
  {
    const int h0 = tid << 1;
    float acc[16][2];
    #pragma unroll
    for (int sl = 0; sl < 16; ++sl){ acc[sl][0] = 0.f; acc[sl][1] = 0.f; }
    const ushort* ecol = enc + ((size_t)b << 9) + h0;
    for (int t = 0; t < 128; ++t){
      uint v = *(const uint*)(ecol + (size_t)t * 16384);
      const float e0 = bfl(v), e1 = bfh(v);
      #pragma unroll
      for (int sl = 0; sl < 16; ++sl){
        const float p = P[sl * 128 + t];
        acc[sl][0] += p * e0; acc[sl][1] += p * e1;
      }
    }
    #pragma unroll
    for (int sl = 0; sl < 16; ++sl){
      const int mm = (s0 + sl) * 32 + b;
      uint u = ((uint)f2bf(acc[sl][1]) << 16) | (uint)f2bf(acc[sl][0]);
      *(uint*)(Ac + (size_t)mm * 1024 + h0) = u;
    }
  }
}

// ---------------- per-row online logsumexp over 32000 ----------------
__global__ __launch_bounds__(256) void k_lse(const float* __restrict__ out, float* __restrict__ lse){
  const int row = blockIdx.x, tid = threadIdx.x;
  const float* p = out + (size_t)row * VD;
  float m = -1e30f, l = 0.f;
  for (int i4 = tid; i4 < VD / 4; i4 += 256){
    f32x4 v = *(const f32x4*)(p + ((size_t)i4 << 2));
    float m4 = fmaxf(fmaxf(v[0], v[1]), fmaxf(v[2], v[3]));
    float s4 = __expf(v[0] - m4) + __expf(v[1] - m4) + __expf(v[2] - m4) + __expf(v[3] - m4);
    if (m4 > m){ l = l * __expf(m - m4) + s4; m = m4; }
    else l += s4 * __expf(m4 - m);
  }
  #pragma unroll
  for (int off = 32; off; off >>= 1){
    float m2 = __shfl_xor(m, off), l2 = __shfl_xor(l, off);
    float nm = fmaxf(m, m2);
    l = l * __expf(m - nm) + l2 * __expf(m2 - nm);
    m = nm;
  }
  __shared__ float rm[4], rl[4];
  if ((tid & 63) == 0){ rm[tid >> 6] = m; rl[tid >> 6] = l; }
  __syncthreads();
  if (tid == 0){
    float M = rm[0], L = rl[0];
    for (int w = 1; w < 4; ++w){
      float nm = fmaxf(M, rm[w]);
      L = L * __expf(M - nm) + rl[w] * __expf(rm[w] - nm);
      M = nm;
    }
    lse[row] = M + __logf(L);
  }
}

// ---------------- in-place subtract lse ----------------
__global__ __launch_bounds__(256) void k_sub(float* __restrict__ out, const float* __restrict__ lse){
  const int row = blockIdx.x;
  const float s = lse[row];
  float* p = out + (size_t)row * VD;
  for (int i4 = threadIdx.x; i4 < VD / 4; i4 += 256){
    f32x4 v = *(const f32x4*)(p + ((size_t)i4 << 2));
    v[0] -= s; v[1] -= s; v[2] -= s; v[3] -= s;
    *(f32x4*)(p + ((size_t)i4 << 2)) = v;
  }
}

extern "C" void kernel_launch(void* const* d_in, const int* in_sizes, int n_in,
                              void* d_out, int out_size, void* d_ws, size_t ws_size,
                              hipStream_t stream){
  const int*   enc_in  = (const int*)d_in[0];
  const int*   dec_in  = (const int*)d_in[1];
  const float* enc_emb = (const float*)d_in[2];
  const float* dec_emb = (const float*)d_in[3];
  const float* WihE    = (const float*)d_in[4];
  const float* WhhE    = (const float*)d_in[5];
  const float* WihD    = (const float*)d_in[6];
  const float* WhhD    = (const float*)d_in[7];
  const float* We      = (const float*)d_in[8];
  const float* be      = (const float*)d_in[9];
  const float* Wd      = (const float*)d_in[10];
  const float* bd      = (const float*)d_in[11];
  const float* outW    = (const float*)d_in[12];
  const float* outb    = (const float*)d_in[13];
  float* out = (float*)d_out;

  char* ws = (char*)d_ws;
  size_t off = 0;
  auto alloc = [&](size_t bytes){ void* p = ws + off; off += (bytes + 255) & ~(size_t)255; return p; };
  ushort* xe    = (ushort*)alloc((size_t)MM * HH * 2);
  ushort* xd    = (ushort*)alloc((size_t)MM * HH * 2);
  ushort* WihEb = (ushort*)alloc((size_t)2048 * 512 * 2);
  ushort* WihDb = (ushort*)alloc((size_t)2048 * 512 * 2);
  ushort* Bc    = (ushort*)alloc((size_t)512 * 1024 * 2);
  float*  bsum  = (float*)alloc(512 * 4);
  ushort* outWb = (ushort*)alloc((size_t)VD * HH * 2);
  ushort* encO  = (ushort*)alloc((size_t)MM * HH * 2);
  ushort* decO  = (ushort*)alloc((size_t)MM * HH * 2);
  u64*    hbuf  = (u64*)alloc(2 * BB * HH * 2);       // 64 KB double buffer
  uint*   tags  = (uint*)alloc(256);
  ushort* Ac    = (ushort*)alloc((size_t)MM * 1024 * 2);
  ushort* hid   = (ushort*)alloc((size_t)MM * HH * 2);
  float*  lse   = (float*)alloc(MM * 4);
  // Gin buffers (67 MB) live in d_out-as-scratch: dead before logits GEMM writes d_out.
  float* GinE = out;
  float* GinD = out + (size_t)MM * 2048;

  k_init<<<dim3(32), dim3(256), 0, stream>>>(hbuf, tags);
  k_cvt<<<dim3(1024), dim3(256), 0, stream>>>(WihE, WihEb, 2048 * 512 / 4);
  k_cvt<<<dim3(1024), dim3(256), 0, stream>>>(WihD, WihDb, 2048 * 512 / 4);
  k_cvt<<<dim3(2048), dim3(256), 0, stream>>>(outW, outWb, VD * HH / 4);
  k_concatB<<<dim3(512), dim3(128), 0, stream>>>(We, Wd, Bc);
  k_bsum<<<dim3(2), dim3(256), 0, stream>>>(be, bd, bsum);
  k_embed<<<dim3(MM), dim3(128), 0, stream>>>(enc_in, enc_emb, xe);
  k_embed<<<dim3(MM), dim3(128), 0, stream>>>(dec_in, dec_emb, xd);
  // input projections: Gin = x @ Wih^T   [4096,512]x[2048,512]^T
  k_gemm<false, false, false><<<dim3(16, 32), dim3(256), 0, stream>>>(xe, WihEb, (const float*)nullptr, GinE, MM, 2048, 512);
  k_gemm<false, false, false><<<dim3(16, 32), dim3(256), 0, stream>>>(xd, WihDb, (const float*)nullptr, GinD, MM, 2048, 512);
  // both LSTMs (persistent, tag-protocol exchange, MFMA recurrence)
  k_lstm<<<dim3(NLB), dim3(512), 0, stream>>>(GinE, GinD, WhhE, WhhD, hbuf, tags, encO, decO, Ac);
  // attention -> ctx into Ac[:, 0:512] (dec h already in Ac[:, 512:1024])
  k_attn<<<dim3(256), dim3(256), 0, stream>>>(encO, decO, Ac);
  // hidden = tanh([ctx|dec] @ [We|Wd]^T + (be+bd))   K=1024 -> bf16
  k_gemm<true, true, true><<<dim3(4, 32), dim3(256), 0, stream>>>(Ac, Bc, bsum, hid, MM, 512, 1024);
  // logits = hidden @ outW^T + out_b -> d_out (f32)
  k_gemm<true, false, false><<<dim3(250, 32), dim3(256), 0, stream>>>(hid, outWb, outb, out, MM, VD, 512);
  // log-softmax
  k_lse<<<dim3(MM), dim3(256), 0, stream>>>(out, lse);
  k_sub<<<dim3(MM), dim3(256), 0, stream>>>(out, lse);
}

// Round 3
// 3424.194 us; speedup vs baseline: 1.2925x; 1.1042x over previous
//
#include <hip/hip_runtime.h>
#include <stdint.h>

#define TT 128
#define BB 32
#define HH 512
#define MM 4096            // T*B == S*B
#define VD 32000
#define NLB 32             // persistent LSTM blocks (one j-slice of 16 h-units each)

typedef float f32x4 __attribute__((ext_vector_type(4)));
typedef short s16x8 __attribute__((ext_vector_type(8)));
typedef unsigned long long u64;

__device__ __forceinline__ ushort f2bf(float f){
  uint u = __float_as_uint(f);
  return (ushort)((u + 0x7fffu + ((u >> 16) & 1u)) >> 16);   // RTNE
}
__device__ __forceinline__ float bfl(uint v){ return __uint_as_float(v << 16); }
__device__ __forceinline__ float bfh(uint v){ return __uint_as_float(v & 0xffff0000u); }
__device__ __forceinline__ float bfu(ushort v){ return __uint_as_float(((uint)v) << 16); }

// ---------------- init: zero h double-buffer + tags ----------------
__global__ void k_init(u64* hbuf, uint* tags){
  int i = blockIdx.x * 256 + threadIdx.x;
  if (i < 8192) hbuf[i] = 0ull;          // 2 x 32 x 512 bf16 = 64 KB
  if (i < NLB) tags[i] = 0u;
}

// ---------------- f32 -> bf16 convert ----------------
__global__ __launch_bounds__(256) void k_cvt(const float* __restrict__ s, ushort* __restrict__ d, int n4){
  int i = blockIdx.x * 256 + threadIdx.x;
  int st = gridDim.x * 256;
  for (; i < n4; i += st){
    f32x4 v = *(const f32x4*)(s + (size_t)i * 4);
    ushort4 o; o.x = f2bf(v[0]); o.y = f2bf(v[1]); o.z = f2bf(v[2]); o.w = f2bf(v[3]);
    *(ushort4*)(d + (size_t)i * 4) = o;
  }
}

// ---------------- embedding gather -> bf16 ----------------
__global__ __launch_bounds__(128) void k_embed(const int* __restrict__ ids, const float* __restrict__ emb,
                                               ushort* __restrict__ out){
  int row = blockIdx.x, t = threadIdx.x;     // 4096 rows, 128 thr
  int id = ids[row];
  f32x4 v = *(const f32x4*)(emb + (size_t)id * HH + t * 4);
  ushort4 o; o.x = f2bf(v[0]); o.y = f2bf(v[1]); o.z = f2bf(v[2]); o.w = f2bf(v[3]);
  *(ushort4*)(out + (size_t)row * HH + t * 4) = o;
}

// ---------------- build concat weight [512][1024] = [We | Wd] ----------------
__global__ __launch_bounds__(128) void k_concatB(const float* __restrict__ We, const float* __restrict__ Wd,
                                                 ushort* __restrict__ Bc){
  int n = blockIdx.x, t = threadIdx.x;       // 512 rows, 128 thr
  f32x4 a = *(const f32x4*)(We + (size_t)n * HH + t * 4);
  f32x4 b = *(const f32x4*)(Wd + (size_t)n * HH + t * 4);
  ushort4 oa, ob;
  oa.x = f2bf(a[0]); oa.y = f2bf(a[1]); oa.z = f2bf(a[2]); oa.w = f2bf(a[3]);
  ob.x = f2bf(b[0]); ob.y = f2bf(b[1]); ob.z = f2bf(b[2]); ob.w = f2bf(b[3]);
  *(ushort4*)(Bc + (size_t)n * 1024 + t * 4) = oa;
  *(ushort4*)(Bc + (size_t)n * 1024 + 512 + t * 4) = ob;
}
__global__ void k_bsum(const float* a, const float* b, float* o){
  int i = blockIdx.x * 256 + threadIdx.x;
  if (i < HH) o[i] = a[i] + b[i];
}

// ---------------- bf16 MFMA GEMM, C = A[M,K] * B[N,K]^T (+bias)(+tanh)(+lse partials) ----------------
template<bool BIAS, bool TANH, bool OUTBF, bool LSE>
__global__ __launch_bounds__(256) void k_gemm(const ushort* __restrict__ A, const ushort* __restrict__ Bm,
                                              const float* __restrict__ bias, void* __restrict__ Cout,
                                              int Mtot, int Ntot, int K,
                                              float* __restrict__ pbufM, float* __restrict__ pbufL){
  __shared__ __align__(16) ushort As[128 * 32];
  __shared__ __align__(16) ushort Bs[128 * 32];
  __shared__ float sMm[2][128], sMl[2][128];
  const int tid = threadIdx.x;
  const int m0 = blockIdx.y << 7, n0 = blockIdx.x << 7;
  const int wid = tid >> 6, lane = tid & 63;
  const int wm = wid >> 1, wn = wid & 1;
  const int lr = lane & 15, lg = lane >> 4;
  const int lk = lg << 3, cr = lg << 2;
  f32x4 acc[4][4];
  for (int i = 0; i < 4; ++i)
    for (int j = 0; j < 4; ++j)
      acc[i][j] = (f32x4){0.f, 0.f, 0.f, 0.f};
  const int c0 = tid, c1 = tid + 256;
  const size_t ar0 = (size_t)(m0 + (c0 >> 2)) * K + ((c0 & 3) << 3);
  const size_t ar1 = (size_t)(m0 + (c1 >> 2)) * K + ((c1 & 3) << 3);
  const size_t br0 = (size_t)(n0 + (c0 >> 2)) * K + ((c0 & 3) << 3);
  const size_t br1 = (size_t)(n0 + (c1 >> 2)) * K + ((c1 & 3) << 3);
  for (int k0 = 0; k0 < K; k0 += 32){
    __syncthreads();
    __builtin_amdgcn_global_load_lds((const __attribute__((address_space(1))) void*)(A + ar0 + k0),
                                     (__attribute__((address_space(3))) void*)(As + (c0 << 3)), 16, 0, 0);
    __builtin_amdgcn_global_load_lds((const __attribute__((address_space(1))) void*)(A + ar1 + k0),
                                     (__attribute__((address_space(3))) void*)(As + (c1 << 3)), 16, 0, 0);
    __builtin_amdgcn_global_load_lds((const __attribute__((address_space(1))) void*)(Bm + br0 + k0),
                                     (__attribute__((address_space(3))) void*)(Bs + (c0 << 3)), 16, 0, 0);
    __builtin_amdgcn_global_load_lds((const __attribute__((address_space(1))) void*)(Bm + br1 + k0),
                                     (__attribute__((address_space(3))) void*)(Bs + (c1 << 3)), 16, 0, 0);
    __syncthreads();
    s16x8 af[4], bf[4];
    #pragma unroll
    for (int f = 0; f < 4; ++f){
      af[f] = *(const s16x8*)(As + ((wm << 6) + (f << 4) + lr) * 32 + lk);
      bf[f] = *(const s16x8*)(Bs + ((wn << 6) + (f << 4) + lr) * 32 + lk);
    }
    #pragma unroll
    for (int fm = 0; fm < 4; ++fm)
      #pragma unroll
      for (int fn = 0; fn < 4; ++fn)
        acc[fm][fn] = __builtin_amdgcn_mfma_f32_16x16x32_bf16(af[fm], bf[fn], acc[fm][fn], 0, 0, 0);
  }
  float bv4[4];
  #pragma unroll
  for (int fn = 0; fn < 4; ++fn)
    bv4[fn] = BIAS ? bias[n0 + (wn << 6) + (fn << 4) + lr] : 0.f;
  float mv[16], lv[16];
  #pragma unroll
  for (int fm = 0; fm < 4; ++fm){
    #pragma unroll
    for (int r = 0; r < 4; ++r){
      const int rw = m0 + (wm << 6) + (fm << 4) + cr + r;
      float vs[4], vmax = -1e30f;
      #pragma unroll
      for (int fn = 0; fn < 4; ++fn){
        float v = acc[fm][fn][r] + bv4[fn];
        if (TANH) v = tanhf(v);
        vs[fn] = v;
        if (LSE) vmax = fmaxf(vmax, v);
        const size_t off = (size_t)rw * Ntot + (n0 + (wn << 6) + (fn << 4) + lr);
        if (OUTBF) ((ushort*)Cout)[off] = f2bf(v);
        else       ((float*)Cout)[off] = v;
      }
      if (LSE){
        float l4 = 0.f;
        #pragma unroll
        for (int fn = 0; fn < 4; ++fn) l4 += __expf(vs[fn] - vmax);
        mv[(fm << 2) + r] = vmax; lv[(fm << 2) + r] = l4;
      }
    }
  }
  if (LSE){
    // merge over the 16 lr lanes (cols of this wave); rows are identical across lr
    #pragma unroll
    for (int q = 0; q < 16; ++q){
      #pragma unroll
      for (int off = 1; off < 16; off <<= 1){
        float m2 = __shfl_xor(mv[q], off), l2 = __shfl_xor(lv[q], off);
        float nm = fmaxf(mv[q], m2);
        lv[q] = lv[q] * __expf(mv[q] - nm) + l2 * __expf(m2 - nm);
        mv[q] = nm;
      }
    }
    // lane lr takes pair q=lr (static-index select to avoid scratch)
    float selM = -1e30f, selL = 0.f;
    #pragma unroll
    for (int q = 0; q < 16; ++q){
      selM = (lr == q) ? mv[q] : selM;
      selL = (lr == q) ? lv[q] : selL;
    }
    const int lrow = (wm << 6) + ((lr >> 2) << 4) + (lg << 2) + (lr & 3);
    sMm[wn][lrow] = selM; sMl[wn][lrow] = selL;
    __syncthreads();
    if (tid < 128){
      float ma = sMm[0][tid], mb = sMm[1][tid];
      float nm = fmaxf(ma, mb);
      float l = sMl[0][tid] * __expf(ma - nm) + sMl[1][tid] * __expf(mb - nm);
      pbufM[(size_t)(m0 + tid) * 256 + blockIdx.x] = nm;
      pbufL[(size_t)(m0 + tid) * 256 + blockIdx.x] = l;
    }
  }
}

// ---------------- persistent LSTM: 32 blocks x 512 thr, MFMA recurrence ----------------
// Block bk owns h-units J = [bk*16, bk*16+16). Wave w = (m = w&1 batch-half, g = w>>1 gate).
// All cross-block state exchanged as native u64 agent-scope atomics (no sub-word CAS!).
// Combine threads (tid<128): one (batch, j-quad) each; h packed 4xbf16 per u64.
__global__ __launch_bounds__(512) void k_lstm(const float* __restrict__ GinE, const float* __restrict__ GinD,
                                              const float* __restrict__ WhhE, const float* __restrict__ WhhD,
                                              u64* __restrict__ hbuf, uint* __restrict__ tags,
                                              ushort* __restrict__ encO, ushort* __restrict__ decO,
                                              ushort* __restrict__ Ac){
  __shared__ float gbuf[2048];              // [g][b][j] f32, 8 KB
  const int tid = threadIdx.x;
  const int bk = blockIdx.x;
  const int J0 = bk << 4;
  const int w = tid >> 6, lane = tid & 63;
  const int m = w & 1, g = w >> 1;
  const int lr = lane & 15, lg = lane >> 4;
  const int bb = tid >> 2, jq = tid & 3;    // combine mapping (tid<128): batch, j-quad

  f32x4 c4 = {0.f, 0.f, 0.f, 0.f};         // 4 cell states per combine thread
  s16x8 bhi[16], blo[16];                   // Whh fragments, persistent in VGPRs/AGPRs
  f32x4 gin4[4];                            // Gin prefetch, [gate]

  if (tid < 128){                           // prologue: Gin for s=0
    const float* gp = GinE + (size_t)bb * 2048 + J0 + (jq << 2);
    gin4[0] = *(const f32x4*)(gp);
    gin4[1] = *(const f32x4*)(gp + 512);
    gin4[2] = *(const f32x4*)(gp + 1024);
    gin4[3] = *(const f32x4*)(gp + 1536);
  }

  for (int s = 0; s < 256; ++s){
    const int ph = s >> 7, t = s & 127;
    if (t == 0){                            // (re)load weight fragments at phase start
      const float* Whh = ph ? WhhD : WhhE;
      const float* wr = Whh + (size_t)(g * 512 + J0 + lr) * 512 + (lg << 3);
      #pragma unroll
      for (int ks = 0; ks < 16; ++ks){
        f32x4 w0 = *(const f32x4*)(wr + ks * 32);
        f32x4 w1 = *(const f32x4*)(wr + ks * 32 + 4);
        s16x8 h8, l8;
        #pragma unroll
        for (int e = 0; e < 4; ++e){
          ushort hv = f2bf(w0[e]); h8[e] = (short)hv; l8[e] = (short)f2bf(w0[e] - bfu(hv));
          ushort hv2 = f2bf(w1[e]); h8[4 + e] = (short)hv2; l8[4 + e] = (short)f2bf(w1[e] - bfu(hv2));
        }
        bhi[ks] = h8; blo[ks] = l8;
      }
    }
    if (s > 0){                             // wait: all blocks published h(s)
      const uint sv = (uint)(s << 1);       // 2 wave-signals per block per step
      for (;;){
        uint v = __hip_atomic_load(tags + (lane & 31), __ATOMIC_RELAXED, __HIP_MEMORY_SCOPE_AGENT);
        if (__all(v >= sv)) break;
        __builtin_amdgcn_s_sleep(1);
      }
      asm volatile("" ::: "memory");        // no hoisting of h loads above the poll
    }
    // ---- A-fragments of h(s) straight from LLC, then split-bf16 MFMA ----
    f32x4 acc = {0.f, 0.f, 0.f, 0.f};
    const u64* hp = hbuf + ((size_t)(s & 1) << 12) + ((m * 16 + lr) << 7) + (lg << 1);
    #pragma unroll
    for (int kb = 0; kb < 4; ++kb){
      u64 av[8];
      #pragma unroll
      for (int q = 0; q < 4; ++q){
        av[2 * q]     = __hip_atomic_load(hp + (kb * 4 + q) * 8,     __ATOMIC_RELAXED, __HIP_MEMORY_SCOPE_AGENT);
        av[2 * q + 1] = __hip_atomic_load(hp + (kb * 4 + q) * 8 + 1, __ATOMIC_RELAXED, __HIP_MEMORY_SCOPE_AGENT);
      }
      #pragma unroll
      for (int q = 0; q < 4; ++q){
        union { u64 q2[2]; s16x8 v; } u;
        u.q2[0] = av[2 * q]; u.q2[1] = av[2 * q + 1];
        acc = __builtin_amdgcn_mfma_f32_16x16x32_bf16(u.v, bhi[kb * 4 + q], acc, 0, 0, 0);
        acc = __builtin_amdgcn_mfma_f32_16x16x32_bf16(u.v, blo[kb * 4 + q], acc, 0, 0, 0);
      }
    }
    // D-frag: j = lane&15, b = m*16 + lg*4 + r  -> gbuf[g][b][j]
    #pragma unroll
    for (int r = 0; r < 4; ++r)
      gbuf[g * 512 + (m * 16 + lg * 4 + r) * 16 + lr] = acc[r];
    __syncthreads();
    // ---- gate combine + state update: thread (bb, jq), 4 units each ----
    if (tid < 128){
      f32x4 z0 = *(const f32x4*)(gbuf +        bb * 16 + (jq << 2));
      f32x4 z1 = *(const f32x4*)(gbuf +  512 + bb * 16 + (jq << 2));
      f32x4 z2 = *(const f32x4*)(gbuf + 1024 + bb * 16 + (jq << 2));
      f32x4 z3 = *(const f32x4*)(gbuf + 1536 + bb * 16 + (jq << 2));
      z0 += gin4[0]; z1 += gin4[1]; z2 += gin4[2]; z3 += gin4[3];
      ushort4 hp4;
      #pragma unroll
      for (int e = 0; e < 4; ++e){
        const float si = 1.f / (1.f + __expf(-z0[e]));
        const float sf = 1.f / (1.f + __expf(-z1[e]));
        const float so = 1.f / (1.f + __expf(-z3[e]));
        const float cc = sf * c4[e] + si * tanhf(z2[e]);
        c4[e] = cc;
        ((ushort*)&hp4)[e] = f2bf(so * tanhf(cc));
      }
      const u64 hword = *(const u64*)&hp4;
      // critical-path store: next-step h
      __hip_atomic_store(hbuf + (((s + 1) & 1) << 12) + (bb << 7) + (bk << 2) + jq, hword,
                         __ATOMIC_RELAXED, __HIP_MEMORY_SCOPE_AGENT);
      asm volatile("s_waitcnt vmcnt(0)" ::: "memory");
      if ((tid & 63) == 0)
        __hip_atomic_fetch_add(tags + bk, 1u, __ATOMIC_RELAXED, __HIP_MEMORY_SCOPE_AGENT);
      // off-critical-path stores (drained by next step's waitcnt / kernel end)
      u64* hallq = (u64*)(ph ? decO : encO);
      __hip_atomic_store(hallq + (size_t)(t * 32 + bb) * 128 + (bk << 2) + jq, hword,
                         __ATOMIC_RELAXED, __HIP_MEMORY_SCOPE_AGENT);
      if (ph)
        __hip_atomic_store((u64*)Ac + (size_t)(t * 32 + bb) * 256 + 128 + (bk << 2) + jq, hword,
                           __ATOMIC_RELAXED, __HIP_MEMORY_SCOPE_AGENT);
      if (s < 255){                         // prefetch Gin(s+1)
        const int s2 = s + 1, t2 = s2 & 127;
        const float* G2 = (s2 >> 7) ? GinD : GinE;
        const float* gp = G2 + (size_t)(t2 * 32 + bb) * 2048 + J0 + (jq << 2);
        gin4[0] = *(const f32x4*)(gp);
        gin4[1] = *(const f32x4*)(gp + 512);
        gin4[2] = *(const f32x4*)(gp + 1024);
        gin4[3] = *(const f32x4*)(gp + 1536);
      }
    }
  }
}

// ---------------- fused attention: scores -> softmax -> ctx, per (b, s-tile of 16) ----------------
__global__ __launch_bounds__(256) void k_attn(const ushort* __restrict__ enc, const ushort* __restrict__ dec,
                                              ushort* __restrict__ Ac){
  __shared__ __align__(16) float dec_lds[16 * 512];
  __shared__ __align__(16) float P[16 * 128];
  const int tid = threadIdx.x;
  const int b = blockIdx.x & 31, st = blockIdx.x >> 5;
  const int s0 = st << 4;
  for (int j = 0; j < 4; ++j){
    int e8 = tid + (j << 8);
    int sl = e8 >> 6, k = (e8 & 63) << 3;
    uint4 v = *(const uint4*)(dec + ((size_t)((s0 + sl) * 32 + b) << 9) + k);
    float* dst = dec_lds + sl * 512 + k;
    dst[0] = bfl(v.x); dst[1] = bfh(v.x); dst[2] = bfl(v.y); dst[3] = bfh(v.y);
    dst[4] = bfl(v.z); dst[5] = bfh(v.z); dst[6] = bfl(v.w); dst[7] = bfh(v.w);
  }
  __syncthreads();
  {
    const int tl = tid & 127, sh = tid >> 7;
    const ushort* erow = enc + ((size_t)(tl * 32 + b) << 9);
    float acc8[8] = {0.f, 0.f, 0.f, 0.f, 0.f, 0.f, 0.f, 0.f};
    for (int k = 0; k < 512; k += 8){
      uint4 v = *(const uint4*)(erow + k);
      const float e0 = bfl(v.x), e1 = bfh(v.x), e2 = bfl(v.y), e3 = bfh(v.y);
      const float e4 = bfl(v.z), e5 = bfh(v.z), e6 = bfl(v.w), e7 = bfh(v.w);
      const float* dl = dec_lds + (sh << 3) * 512 + k;
      #pragma unroll
      for (int i = 0; i < 8; ++i){
        f32x4 d0 = *(const f32x4*)(dl + i * 512);
        f32x4 d1 = *(const f32x4*)(dl + i * 512 + 4);
        acc8[i] += d0[0]*e0 + d0[1]*e1 + d0[2]*e2 + d0[3]*e3
                 + d1[0]*e4 + d1[1]*e5 + d1[2]*e6 + d1[3]*e7;
      }
    }
    #pragma unroll
    for (int i = 0; i < 8; ++i) P[((sh << 3) + i) * 128 + tl] = acc8[i];
  }
  __syncthreads();
  {
    const int r = tid >> 4, i = tid & 15;
    float* prow = P + r * 128 + (i << 3);
    float v[8], mx = -1e30f;
    #pragma unroll
    for (int j = 0; j < 8; ++j){ v[j] = prow[j]; mx = fmaxf(mx, v[j]); }
    #pragma unroll
    for (int off = 1; off < 16; off <<= 1) mx = fmaxf(mx, __shfl_xor(mx, off));
    float l = 0.f;
    #pragma unroll
    for (int j = 0; j < 8; ++j){ v[j] = __expf(v[j] - mx); l += v[j]; }
    #pragma unroll
    for (int off = 1; off < 16; off <<= 1) l += __shfl_xor(l, off);
    const float inv = 1.f / l;
    #pragma unroll
    for (int j = 0; j < 8; ++j) prow[j] = v[j] * inv;
  }
  __syncthreads();
  {
    const int h0 = tid << 1;
    float acc[16][2];
    #pragma unroll
    for (int sl = 0; sl < 16; ++sl){ acc[sl][0] = 0.f; acc[sl][1] = 0.f; }
    const ushort* ecol = enc + ((size_t)b << 9) + h0;
    for (int t = 0; t < 128; ++t){
      uint v = *(const uint*)(ecol + (size_t)t * 16384);
      const float e0 = bfl(v), e1 = bfh(v);
      #pragma unroll
      for (int sl = 0; sl < 16; ++sl){
        const float p = P[sl * 128 + t];
        acc[sl][0] += p * e0; acc[sl][1] += p * e1;
      }
    }
    #pragma unroll
    for (int sl = 0; sl < 16; ++sl){
      const int mm = (s0 + sl) * 32 + b;
      uint u = ((uint)f2bf(acc[sl][1]) << 16) | (uint)f2bf(acc[sl][0]);
      *(uint*)(Ac + (size_t)mm * 1024 + h0) = u;
    }
  }
}

// ---------------- reduce per-tile (m,l) partials -> lse[row] ----------------
__global__ __launch_bounds__(256) void k_lse2(const float* __restrict__ pM, const float* __restrict__ pL,
                                              float* __restrict__ lse){
  const int row = (blockIdx.x << 2) + (threadIdx.x >> 6);
  const int lane = threadIdx.x & 63;
  float m = -1e30f, l = 0.f;
  for (int i = lane; i < 250; i += 64){
    float m2 = pM[(size_t)row * 256 + i], l2 = pL[(size_t)row * 256 + i];
    float nm = fmaxf(m, m2);
    l = l * __expf(m - nm) + l2 * __expf(m2 - nm);
    m = nm;
  }
  #pragma unroll
  for (int off = 32; off; off >>= 1){
    float m2 = __shfl_xor(m, off), l2 = __shfl_xor(l, off);
    float nm = fmaxf(m, m2);
    l = l * __expf(m - nm) + l2 * __expf(m2 - nm);
    m = nm;
  }
  if (lane == 0) lse[row] = m + __logf(l);
}

// ---------------- in-place subtract lse ----------------
__global__ __launch_bounds__(256) void k_sub(float* __restrict__ out, const float* __restrict__ lse){
  const int row = blockIdx.x;
  const float s = lse[row];
  float* p = out + (size_t)row * VD;
  for (int i4 = threadIdx.x; i4 < VD / 4; i4 += 256){
    f32x4 v = *(const f32x4*)(p + ((size_t)i4 << 2));
    v[0] -= s; v[1] -= s; v[2] -= s; v[3] -= s;
    *(f32x4*)(p + ((size_t)i4 << 2)) = v;
  }
}

extern "C" void kernel_launch(void* const* d_in, const int* in_sizes, int n_in,
                              void* d_out, int out_size, void* d_ws, size_t ws_size,
                              hipStream_t stream){
  const int*   enc_in  = (const int*)d_in[0];
  const int*   dec_in  = (const int*)d_in[1];
  const float* enc_emb = (const float*)d_in[2];
  const float* dec_emb = (const float*)d_in[3];
  const float* WihE    = (const float*)d_in[4];
  const float* WhhE    = (const float*)d_in[5];
  const float* WihD    = (const float*)d_in[6];
  const float* WhhD    = (const float*)d_in[7];
  const float* We      = (const float*)d_in[8];
  const float* be      = (const float*)d_in[9];
  const float* Wd      = (const float*)d_in[10];
  const float* bd      = (const float*)d_in[11];
  const float* outW    = (const float*)d_in[12];
  const float* outb    = (const float*)d_in[13];
  float* out = (float*)d_out;

  char* ws = (char*)d_ws;
  size_t off = 0;
  auto alloc = [&](size_t bytes){ void* p = ws + off; off += (bytes + 255) & ~(size_t)255; return p; };
  ushort* xe    = (ushort*)alloc((size_t)MM * HH * 2);
  ushort* xd    = (ushort*)alloc((size_t)MM * HH * 2);
  ushort* WihEb = (ushort*)alloc((size_t)2048 * 512 * 2);
  ushort* WihDb = (ushort*)alloc((size_t)2048 * 512 * 2);
  ushort* Bc    = (ushort*)alloc((size_t)512 * 1024 * 2);
  float*  bsum  = (float*)alloc(512 * 4);
  ushort* outWb = (ushort*)alloc((size_t)VD * HH * 2);
  ushort* encO  = (ushort*)alloc((size_t)MM * HH * 2);
  ushort* decO  = (ushort*)alloc((size_t)MM * HH * 2);
  u64*    hbuf  = (u64*)alloc(2 * BB * HH * 2);       // 64 KB double buffer
  uint*   tags  = (uint*)alloc(256);
  ushort* Ac    = (ushort*)alloc((size_t)MM * 1024 * 2);
  ushort* hid   = (ushort*)alloc((size_t)MM * HH * 2);
  float*  lse   = (float*)alloc(MM * 4);
  float*  pbufM = (float*)alloc((size_t)MM * 256 * 4); // 4 MB
  float*  pbufL = (float*)alloc((size_t)MM * 256 * 4); // 4 MB
  // Gin buffers (67 MB) live in d_out-as-scratch: dead before logits GEMM writes d_out.
  float* GinE = out;
  float* GinD = out + (size_t)MM * 2048;

  k_init<<<dim3(32), dim3(256), 0, stream>>>(hbuf, tags);
  k_cvt<<<dim3(1024), dim3(256), 0, stream>>>(WihE, WihEb, 2048 * 512 / 4);
  k_cvt<<<dim3(1024), dim3(256), 0, stream>>>(WihD, WihDb, 2048 * 512 / 4);
  k_cvt<<<dim3(2048), dim3(256), 0, stream>>>(outW, outWb, VD * HH / 4);
  k_concatB<<<dim3(512), dim3(128), 0, stream>>>(We, Wd, Bc);
  k_bsum<<<dim3(2), dim3(256), 0, stream>>>(be, bd, bsum);
  k_embed<<<dim3(MM), dim3(128), 0, stream>>>(enc_in, enc_emb, xe);
  k_embed<<<dim3(MM), dim3(128), 0, stream>>>(dec_in, dec_emb, xd);
  // input projections: Gin = x @ Wih^T   [4096,512]x[2048,512]^T
  k_gemm<false, false, false, false><<<dim3(16, 32), dim3(256), 0, stream>>>(xe, WihEb, (const float*)nullptr, GinE, MM, 2048, 512, nullptr, nullptr);
  k_gemm<false, false, false, false><<<dim3(16, 32), dim3(256), 0, stream>>>(xd, WihDb, (const float*)nullptr, GinD, MM, 2048, 512, nullptr, nullptr);
  // both LSTMs (persistent, tag-protocol exchange, MFMA recurrence)
  k_lstm<<<dim3(NLB), dim3(512), 0, stream>>>(GinE, GinD, WhhE, WhhD, hbuf, tags, encO, decO, Ac);
  // attention -> ctx into Ac[:, 0:512] (dec h already in Ac[:, 512:1024])
  k_attn<<<dim3(256), dim3(256), 0, stream>>>(encO, decO, Ac);
  // hidden = tanh([ctx|dec] @ [We|Wd]^T + (be+bd))   K=1024 -> bf16
  k_gemm<true, true, true, false><<<dim3(4, 32), dim3(256), 0, stream>>>(Ac, Bc, bsum, hid, MM, 512, 1024, nullptr, nullptr);
  // logits = hidden @ outW^T + out_b -> d_out (f32), + per-tile lse partials
  k_gemm<true, false, false, true><<<dim3(250, 32), dim3(256), 0, stream>>>(hid, outWb, outb, out, MM, VD, 512, pbufM, pbufL);
  // log-softmax
  k_lse2<<<dim3(1024), dim3(256), 0, stream>>>(pbufM, pbufL, lse);
  k_sub<<<dim3(MM), dim3(256), 0, stream>>>(out, lse);
}

// Round 4
// 3125.542 us; speedup vs baseline: 1.4160x; 1.0956x over previous
//
#include <hip/hip_runtime.h>
#include <stdint.h>

#define TT 128
#define BB 32
#define HH 512
#define MM 4096            // T*B == S*B
#define VD 32000
#define NLB 32             // persistent LSTM blocks (one j-slice of 16 h-units each)

typedef float f32x4 __attribute__((ext_vector_type(4)));
typedef short s16x8 __attribute__((ext_vector_type(8)));
typedef unsigned long long u64;

__device__ __forceinline__ ushort f2bf(float f){
  uint u = __float_as_uint(f);
  return (ushort)((u + 0x7fffu + ((u >> 16) & 1u)) >> 16);   // RTNE
}
__device__ __forceinline__ float bfl(uint v){ return __uint_as_float(v << 16); }
__device__ __forceinline__ float bfh(uint v){ return __uint_as_float(v & 0xffff0000u); }
__device__ __forceinline__ float bfu(ushort v){ return __uint_as_float(((uint)v) << 16); }
__device__ __forceinline__ float fast_tanh(float x){
  return 1.f - 2.f / (1.f + __expf(2.f * x));   // exact at saturation, ~1e-6 mid-range
}

// ---------------- init: zero h double-buffer + tags ----------------
__global__ void k_init(u64* hbuf, uint* tags){
  int i = blockIdx.x * 256 + threadIdx.x;
  if (i < 8192) hbuf[i] = 0ull;          // 2 x 32 x 512 bf16 = 64 KB
  if (i < 1024) tags[i] = 0u;            // 32 blocks x 32-dword private lines
}

// ---------------- f32 -> bf16 convert ----------------
__global__ __launch_bounds__(256) void k_cvt(const float* __restrict__ s, ushort* __restrict__ d, int n4){
  int i = blockIdx.x * 256 + threadIdx.x;
  int st = gridDim.x * 256;
  for (; i < n4; i += st){
    f32x4 v = *(const f32x4*)(s + (size_t)i * 4);
    ushort4 o; o.x = f2bf(v[0]); o.y = f2bf(v[1]); o.z = f2bf(v[2]); o.w = f2bf(v[3]);
    *(ushort4*)(d + (size_t)i * 4) = o;
  }
}

// ---------------- embedding gather -> bf16 ----------------
__global__ __launch_bounds__(128) void k_embed(const int* __restrict__ ids, const float* __restrict__ emb,
                                               ushort* __restrict__ out){
  int row = blockIdx.x, t = threadIdx.x;     // 4096 rows, 128 thr
  int id = ids[row];
  f32x4 v = *(const f32x4*)(emb + (size_t)id * HH + t * 4);
  ushort4 o; o.x = f2bf(v[0]); o.y = f2bf(v[1]); o.z = f2bf(v[2]); o.w = f2bf(v[3]);
  *(ushort4*)(out + (size_t)row * HH + t * 4) = o;
}

// ---------------- build concat weight [512][1024] = [We | Wd] ----------------
__global__ __launch_bounds__(128) void k_concatB(const float* __restrict__ We, const float* __restrict__ Wd,
                                                 ushort* __restrict__ Bc){
  int n = blockIdx.x, t = threadIdx.x;       // 512 rows, 128 thr
  f32x4 a = *(const f32x4*)(We + (size_t)n * HH + t * 4);
  f32x4 b = *(const f32x4*)(Wd + (size_t)n * HH + t * 4);
  ushort4 oa, ob;
  oa.x = f2bf(a[0]); oa.y = f2bf(a[1]); oa.z = f2bf(a[2]); oa.w = f2bf(a[3]);
  ob.x = f2bf(b[0]); ob.y = f2bf(b[1]); ob.z = f2bf(b[2]); ob.w = f2bf(b[3]);
  *(ushort4*)(Bc + (size_t)n * 1024 + t * 4) = oa;
  *(ushort4*)(Bc + (size_t)n * 1024 + 512 + t * 4) = ob;
}
__global__ void k_bsum(const float* a, const float* b, float* o){
  int i = blockIdx.x * 256 + threadIdx.x;
  if (i < HH) o[i] = a[i] + b[i];
}

// ---------------- bf16 MFMA GEMM, C = A[M,K] * B[N,K]^T (+bias)(+tanh)(+lse partials) ----------------
template<bool BIAS, bool TANH, bool OUTBF, bool LSE>
__global__ __launch_bounds__(256) void k_gemm(const ushort* __restrict__ A, const ushort* __restrict__ Bm,
                                              const float* __restrict__ bias, void* __restrict__ Cout,
                                              int Mtot, int Ntot, int K,
                                              float* __restrict__ pbufM, float* __restrict__ pbufL){
  __shared__ __align__(16) ushort As[128 * 32];
  __shared__ __align__(16) ushort Bs[128 * 32];
  __shared__ float sMm[2][128], sMl[2][128];
  const int tid = threadIdx.x;
  const int m0 = blockIdx.y << 7, n0 = blockIdx.x << 7;
  const int wid = tid >> 6, lane = tid & 63;
  const int wm = wid >> 1, wn = wid & 1;
  const int lr = lane & 15, lg = lane >> 4;
  const int lk = lg << 3, cr = lg << 2;
  f32x4 acc[4][4];
  for (int i = 0; i < 4; ++i)
    for (int j = 0; j < 4; ++j)
      acc[i][j] = (f32x4){0.f, 0.f, 0.f, 0.f};
  const int c0 = tid, c1 = tid + 256;
  const size_t ar0 = (size_t)(m0 + (c0 >> 2)) * K + ((c0 & 3) << 3);
  const size_t ar1 = (size_t)(m0 + (c1 >> 2)) * K + ((c1 & 3) << 3);
  const size_t br0 = (size_t)(n0 + (c0 >> 2)) * K + ((c0 & 3) << 3);
  const size_t br1 = (size_t)(n0 + (c1 >> 2)) * K + ((c1 & 3) << 3);
  for (int k0 = 0; k0 < K; k0 += 32){
    __syncthreads();
    __builtin_amdgcn_global_load_lds((const __attribute__((address_space(1))) void*)(A + ar0 + k0),
                                     (__attribute__((address_space(3))) void*)(As + (c0 << 3)), 16, 0, 0);
    __builtin_amdgcn_global_load_lds((const __attribute__((address_space(1))) void*)(A + ar1 + k0),
                                     (__attribute__((address_space(3))) void*)(As + (c1 << 3)), 16, 0, 0);
    __builtin_amdgcn_global_load_lds((const __attribute__((address_space(1))) void*)(Bm + br0 + k0),
                                     (__attribute__((address_space(3))) void*)(Bs + (c0 << 3)), 16, 0, 0);
    __builtin_amdgcn_global_load_lds((const __attribute__((address_space(1))) void*)(Bm + br1 + k0),
                                     (__attribute__((address_space(3))) void*)(Bs + (c1 << 3)), 16, 0, 0);
    __syncthreads();
    s16x8 af[4], bf[4];
    #pragma unroll
    for (int f = 0; f < 4; ++f){
      af[f] = *(const s16x8*)(As + ((wm << 6) + (f << 4) + lr) * 32 + lk);
      bf[f] = *(const s16x8*)(Bs + ((wn << 6) + (f << 4) + lr) * 32 + lk);
    }
    #pragma unroll
    for (int fm = 0; fm < 4; ++fm)
      #pragma unroll
      for (int fn = 0; fn < 4; ++fn)
        acc[fm][fn] = __builtin_amdgcn_mfma_f32_16x16x32_bf16(af[fm], bf[fn], acc[fm][fn], 0, 0, 0);
  }
  float bv4[4];
  #pragma unroll
  for (int fn = 0; fn < 4; ++fn)
    bv4[fn] = BIAS ? bias[n0 + (wn << 6) + (fn << 4) + lr] : 0.f;
  float mv[16], lv[16];
  #pragma unroll
  for (int fm = 0; fm < 4; ++fm){
    #pragma unroll
    for (int r = 0; r < 4; ++r){
      const int rw = m0 + (wm << 6) + (fm << 4) + cr + r;
      float vs[4], vmax = -1e30f;
      #pragma unroll
      for (int fn = 0; fn < 4; ++fn){
        float v = acc[fm][fn][r] + bv4[fn];
        if (TANH) v = tanhf(v);
        vs[fn] = v;
        if (LSE) vmax = fmaxf(vmax, v);
        const size_t off = (size_t)rw * Ntot + (n0 + (wn << 6) + (fn << 4) + lr);
        if (OUTBF) ((ushort*)Cout)[off] = f2bf(v);
        else       ((float*)Cout)[off] = v;
      }
      if (LSE){
        float l4 = 0.f;
        #pragma unroll
        for (int fn = 0; fn < 4; ++fn) l4 += __expf(vs[fn] - vmax);
        mv[(fm << 2) + r] = vmax; lv[(fm << 2) + r] = l4;
      }
    }
  }
  if (LSE){
    #pragma unroll
    for (int q = 0; q < 16; ++q){
      #pragma unroll
      for (int off = 1; off < 16; off <<= 1){
        float m2 = __shfl_xor(mv[q], off), l2 = __shfl_xor(lv[q], off);
        float nm = fmaxf(mv[q], m2);
        lv[q] = lv[q] * __expf(mv[q] - nm) + l2 * __expf(m2 - nm);
        mv[q] = nm;
      }
    }
    float selM = -1e30f, selL = 0.f;
    #pragma unroll
    for (int q = 0; q < 16; ++q){
      selM = (lr == q) ? mv[q] : selM;
      selL = (lr == q) ? lv[q] : selL;
    }
    const int lrow = (wm << 6) + ((lr >> 2) << 4) + (lg << 2) + (lr & 3);
    sMm[wn][lrow] = selM; sMl[wn][lrow] = selL;
    __syncthreads();
    if (tid < 128){
      float ma = sMm[0][tid], mb = sMm[1][tid];
      float nm = fmaxf(ma, mb);
      float l = sMl[0][tid] * __expf(ma - nm) + sMl[1][tid] * __expf(mb - nm);
      pbufM[(size_t)(m0 + tid) * 256 + blockIdx.x] = nm;
      pbufL[(size_t)(m0 + tid) * 256 + blockIdx.x] = l;
    }
  }
}

// ---------------- persistent LSTM: 32 blocks x 512 thr, MFMA recurrence ----------------
// Barrier v3: NO atomic RMWs. Each block owns a private 128B tag line; its two combine
// waves plain-store (s+1) into slots 0/1. One poller wave (w==2) per block gathers all
// 32 lines; other waves wait at __syncthreads. h via LLC u64 agent ops, double-buffered.
__global__ __launch_bounds__(512) void k_lstm(const float* __restrict__ GinE, const float* __restrict__ GinD,
                                              const float* __restrict__ WhhE, const float* __restrict__ WhhD,
                                              u64* __restrict__ hbuf, uint* __restrict__ tags,
                                              ushort* __restrict__ encO, ushort* __restrict__ decO,
                                              ushort* __restrict__ Ac){
  __shared__ float gbuf[4 * 640];           // [g][b*20 + j] stride-20 (2-way-free banks), 10 KB
  const int tid = threadIdx.x;
  const int bk = blockIdx.x;
  const int J0 = bk << 4;
  const int w = tid >> 6, lane = tid & 63;
  const int m = w & 1, g = w >> 1;
  const int lr = lane & 15, lg = lane >> 4;
  const int bb = tid >> 2, jq = tid & 3;    // combine mapping (tid<128): batch, j-quad

  f32x4 c4 = {0.f, 0.f, 0.f, 0.f};         // 4 cell states per combine thread
  s16x8 bw[16];                             // Whh bf16 fragments, persistent (64 VGPRs)
  f32x4 gin4[4];

  if (tid < 128){                           // prologue: Gin for s=0
    const float* gp = GinE + (size_t)bb * 2048 + J0 + (jq << 2);
    gin4[0] = *(const f32x4*)(gp);
    gin4[1] = *(const f32x4*)(gp + 512);
    gin4[2] = *(const f32x4*)(gp + 1024);
    gin4[3] = *(const f32x4*)(gp + 1536);
  }

  for (int s = 0; s < 256; ++s){
    const int ph = s >> 7, t = s & 127;
    if (t == 0){                            // (re)load weight fragments at phase start
      const float* Whh = ph ? WhhD : WhhE;
      const float* wr = Whh + (size_t)((g << 9) + J0 + lr) * 512 + (lg << 3);
      #pragma unroll
      for (int ks = 0; ks < 16; ++ks){
        f32x4 w0 = *(const f32x4*)(wr + ks * 32);
        f32x4 w1 = *(const f32x4*)(wr + ks * 32 + 4);
        s16x8 h8;
        #pragma unroll
        for (int e = 0; e < 4; ++e){
          h8[e] = (short)f2bf(w0[e]);
          h8[4 + e] = (short)f2bf(w1[e]);
        }
        bw[ks] = h8;
      }
    }
    // ---- MFMA phase: A-frags of h(s) straight from LLC ----
    f32x4 acc = {0.f, 0.f, 0.f, 0.f};
    {
      const u64* hp = hbuf + ((size_t)(s & 1) << 12) + ((m * 16 + lr) << 7) + (lg << 1);
      #pragma unroll
      for (int kb = 0; kb < 4; ++kb){
        u64 av[8];
        #pragma unroll
        for (int q = 0; q < 4; ++q){
          av[2 * q]     = __hip_atomic_load(hp + (kb * 4 + q) * 8,     __ATOMIC_RELAXED, __HIP_MEMORY_SCOPE_AGENT);
          av[2 * q + 1] = __hip_atomic_load(hp + (kb * 4 + q) * 8 + 1, __ATOMIC_RELAXED, __HIP_MEMORY_SCOPE_AGENT);
        }
        #pragma unroll
        for (int q = 0; q < 4; ++q){
          union { u64 q2[2]; s16x8 v; } u;
          u.q2[0] = av[2 * q]; u.q2[1] = av[2 * q + 1];
          acc = __builtin_amdgcn_mfma_f32_16x16x32_bf16(u.v, bw[kb * 4 + q], acc, 0, 0, 0);
        }
      }
    }
    // D-frag: j = lane&15, b = m*16 + lg*4 + r  -> gbuf[g][b*20 + j]
    #pragma unroll
    for (int r = 0; r < 4; ++r)
      gbuf[g * 640 + (m * 16 + lg * 4 + r) * 20 + lr] = acc[r];
    __syncthreads();                        // sync#1: gbuf ready
    if (w < 2){
      // ---- gate combine + state update: thread (bb, jq), 4 units each ----
      f32x4 z0 = *(const f32x4*)(gbuf +        bb * 20 + (jq << 2));
      f32x4 z1 = *(const f32x4*)(gbuf +  640 + bb * 20 + (jq << 2));
      f32x4 z2 = *(const f32x4*)(gbuf + 1280 + bb * 20 + (jq << 2));
      f32x4 z3 = *(const f32x4*)(gbuf + 1920 + bb * 20 + (jq << 2));
      z0 += gin4[0]; z1 += gin4[1]; z2 += gin4[2]; z3 += gin4[3];
      ushort4 hp4;
      #pragma unroll
      for (int e = 0; e < 4; ++e){
        const float si = 1.f / (1.f + __expf(-z0[e]));
        const float sf = 1.f / (1.f + __expf(-z1[e]));
        const float so = 1.f / (1.f + __expf(-z3[e]));
        const float cc = sf * c4[e] + si * fast_tanh(z2[e]);
        c4[e] = cc;
        ((ushort*)&hp4)[e] = f2bf(so * fast_tanh(cc));
      }
      const u64 hword = *(const u64*)&hp4;
      __hip_atomic_store(hbuf + (((s + 1) & 1) << 12) + (bb << 7) + (bk << 2) + jq, hword,
                         __ATOMIC_RELAXED, __HIP_MEMORY_SCOPE_AGENT);
      asm volatile("s_waitcnt vmcnt(0)" ::: "memory");      // h visible at LLC
      if ((tid & 63) == 0)                                  // plain store, private line, no RMW
        __hip_atomic_store(tags + (bk << 5) + w, (uint)(s + 1),
                           __ATOMIC_RELAXED, __HIP_MEMORY_SCOPE_AGENT);
      // off-critical-path stores
      u64* hallq = (u64*)(ph ? decO : encO);
      __hip_atomic_store(hallq + (size_t)(t * 32 + bb) * 128 + (bk << 2) + jq, hword,
                         __ATOMIC_RELAXED, __HIP_MEMORY_SCOPE_AGENT);
      if (ph)
        __hip_atomic_store((u64*)Ac + (size_t)(t * 32 + bb) * 256 + 128 + (bk << 2) + jq, hword,
                           __ATOMIC_RELAXED, __HIP_MEMORY_SCOPE_AGENT);
      if (s < 255){                         // prefetch Gin(s+1)
        const int s2 = s + 1, t2 = s2 & 127;
        const float* G2 = (s2 >> 7) ? GinD : GinE;
        const float* gp = G2 + (size_t)(t2 * 32 + bb) * 2048 + J0 + (jq << 2);
        gin4[0] = *(const f32x4*)(gp);
        gin4[1] = *(const f32x4*)(gp + 512);
        gin4[2] = *(const f32x4*)(gp + 1024);
        gin4[3] = *(const f32x4*)(gp + 1536);
      }
    } else if (w == 2 && s < 255){
      // ---- single poller wave: lanes gather 32 private lines x 2 slots ----
      const uint sv = (uint)(s + 1);
      const uint* tp = tags + ((lane & 31) << 5) + (lane >> 5);
      for (;;){
        uint v = __hip_atomic_load(tp, __ATOMIC_RELAXED, __HIP_MEMORY_SCOPE_AGENT);
        if (__all(v >= sv)) break;
      }
      asm volatile("" ::: "memory");
    }
    __syncthreads();                        // sync#2: release all waves into step s+1
  }
}

// ---------------- fused attention: scores -> softmax -> ctx, per (b, s-tile of 16) ----------------
__global__ __launch_bounds__(256) void k_attn(const ushort* __restrict__ enc, const ushort* __restrict__ dec,
                                              ushort* __restrict__ Ac){
  __shared__ __align__(16) float dec_lds[16 * 512];
  __shared__ __align__(16) float P[16 * 128];
  const int tid = threadIdx.x;
  const int b = blockIdx.x & 31, st = blockIdx.x >> 5;
  const int s0 = st << 4;
  for (int j = 0; j < 4; ++j){
    int e8 = tid + (j << 8);
    int sl = e8 >> 6, k = (e8 & 63) << 3;
    uint4 v = *(const uint4*)(dec + ((size_t)((s0 + sl) * 32 + b) << 9) + k);
    float* dst = dec_lds + sl * 512 + k;
    dst[0] = bfl(v.x); dst[1] = bfh(v.x); dst[2] = bfl(v.y); dst[3] = bfh(v.y);
    dst[4] = bfl(v.z); dst[5] = bfh(v.z); dst[6] = bfl(v.w); dst[7] = bfh(v.w);
  }
  __syncthreads();
  {
    const int tl = tid & 127, sh = tid >> 7;
    const ushort* erow = enc + ((size_t)(tl * 32 + b) << 9);
    float acc8[8] = {0.f, 0.f, 0.f, 0.f, 0.f, 0.f, 0.f, 0.f};
    for (int k = 0; k < 512; k += 8){
      uint4 v = *(const uint4*)(erow + k);
      const float e0 = bfl(v.x), e1 = bfh(v.x), e2 = bfl(v.y), e3 = bfh(v.y);
      const float e4 = bfl(v.z), e5 = bfh(v.z), e6 = bfl(v.w), e7 = bfh(v.w);
      const float* dl = dec_lds + (sh << 3) * 512 + k;
      #pragma unroll
      for (int i = 0; i < 8; ++i){
        f32x4 d0 = *(const f32x4*)(dl + i * 512);
        f32x4 d1 = *(const f32x4*)(dl + i * 512 + 4);
        acc8[i] += d0[0]*e0 + d0[1]*e1 + d0[2]*e2 + d0[3]*e3
                 + d1[0]*e4 + d1[1]*e5 + d1[2]*e6 + d1[3]*e7;
      }
    }
    #pragma unroll
    for (int i = 0; i < 8; ++i) P[((sh << 3) + i) * 128 + tl] = acc8[i];
  }
  __syncthreads();
  {
    const int r = tid >> 4, i = tid & 15;
    float* prow = P + r * 128 + (i << 3);
    float v[8], mx = -1e30f;
    #pragma unroll
    for (int j = 0; j < 8; ++j){ v[j] = prow[j]; mx = fmaxf(mx, v[j]); }
    #pragma unroll
    for (int off = 1; off < 16; off <<= 1) mx = fmaxf(mx, __shfl_xor(mx, off));
    float l = 0.f;
    #pragma unroll
    for (int j = 0; j < 8; ++j){ v[j] = __expf(v[j] - mx); l += v[j]; }
    #pragma unroll
    for (int off = 1; off < 16; off <<= 1) l += __shfl_xor(l, off);
    const float inv = 1.f / l;
    #pragma unroll
    for (int j = 0; j < 8; ++j) prow[j] = v[j] * inv;
  }
  __syncthreads();
  {
    const int h0 = tid << 1;
    float acc[16][2];
    #pragma unroll
    for (int sl = 0; sl < 16; ++sl){ acc[sl][0] = 0.f; acc[sl][1] = 0.f; }
    const ushort* ecol = enc + ((size_t)b << 9) + h0;
    for (int t = 0; t < 128; ++t){
      uint v = *(const uint*)(ecol + (size_t)t * 16384);
      const float e0 = bfl(v), e1 = bfh(v);
      #pragma unroll
      for (int sl = 0; sl < 16; ++sl){
        const float p = P[sl * 128 + t];
        acc[sl][0] += p * e0; acc[sl][1] += p * e1;
      }
    }
    #pragma unroll
    for (int sl = 0; sl < 16; ++sl){
      const int mm = (s0 + sl) * 32 + b;
      uint u = ((uint)f2bf(acc[sl][1]) << 16) | (uint)f2bf(acc[sl][0]);
      *(uint*)(Ac + (size_t)mm * 1024 + h0) = u;
    }
  }
}

// ---------------- reduce per-tile (m,l) partials -> lse[row] ----------------
__global__ __launch_bounds__(256) void k_lse2(const float* __restrict__ pM, const float* __restrict__ pL,
                                              float* __restrict__ lse){
  const int row = (blockIdx.x << 2) + (threadIdx.x >> 6);
  const int lane = threadIdx.x & 63;
  float m = -1e30f, l = 0.f;
  for (int i = lane; i < 250; i += 64){
    float m2 = pM[(size_t)row * 256 + i], l2 = pL[(size_t)row * 256 + i];
    float nm = fmaxf(m, m2);
    l = l * __expf(m - nm) + l2 * __expf(m2 - nm);
    m = nm;
  }
  #pragma unroll
  for (int off = 32; off; off >>= 1){
    float m2 = __shfl_xor(m, off), l2 = __shfl_xor(l, off);
    float nm = fmaxf(m, m2);
    l = l * __expf(m - nm) + l2 * __expf(m2 - nm);
    m = nm;
  }
  if (lane == 0) lse[row] = m + __logf(l);
}

// ---------------- in-place subtract lse ----------------
__global__ __launch_bounds__(256) void k_sub(float* __restrict__ out, const float* __restrict__ lse){
  const int row = blockIdx.x;
  const float s = lse[row];
  float* p = out + (size_t)row * VD;
  for (int i4 = threadIdx.x; i4 < VD / 4; i4 += 256){
    f32x4 v = *(const f32x4*)(p + ((size_t)i4 << 2));
    v[0] -= s; v[1] -= s; v[2] -= s; v[3] -= s;
    *(f32x4*)(p + ((size_t)i4 << 2)) = v;
  }
}

extern "C" void kernel_launch(void* const* d_in, const int* in_sizes, int n_in,
                              void* d_out, int out_size, void* d_ws, size_t ws_size,
                              hipStream_t stream){
  const int*   enc_in  = (const int*)d_in[0];
  const int*   dec_in  = (const int*)d_in[1];
  const float* enc_emb = (const float*)d_in[2];
  const float* dec_emb = (const float*)d_in[3];
  const float* WihE    = (const float*)d_in[4];
  const float* WhhE    = (const float*)d_in[5];
  const float* WihD    = (const float*)d_in[6];
  const float* WhhD    = (const float*)d_in[7];
  const float* We      = (const float*)d_in[8];
  const float* be      = (const float*)d_in[9];
  const float* Wd      = (const float*)d_in[10];
  const float* bd      = (const float*)d_in[11];
  const float* outW    = (const float*)d_in[12];
  const float* outb    = (const float*)d_in[13];
  float* out = (float*)d_out;

  char* ws = (char*)d_ws;
  size_t off = 0;
  auto alloc = [&](size_t bytes){ void* p = ws + off; off += (bytes + 255) & ~(size_t)255; return p; };
  ushort* xe    = (ushort*)alloc((size_t)MM * HH * 2);
  ushort* xd    = (ushort*)alloc((size_t)MM * HH * 2);
  ushort* WihEb = (ushort*)alloc((size_t)2048 * 512 * 2);
  ushort* WihDb = (ushort*)alloc((size_t)2048 * 512 * 2);
  ushort* Bc    = (ushort*)alloc((size_t)512 * 1024 * 2);
  float*  bsum  = (float*)alloc(512 * 4);
  ushort* outWb = (ushort*)alloc((size_t)VD * HH * 2);
  ushort* encO  = (ushort*)alloc((size_t)MM * HH * 2);
  ushort* decO  = (ushort*)alloc((size_t)MM * HH * 2);
  u64*    hbuf  = (u64*)alloc(2 * BB * HH * 2);       // 64 KB double buffer
  uint*   tags  = (uint*)alloc(4096);                  // 32 x 128B private lines
  ushort* Ac    = (ushort*)alloc((size_t)MM * 1024 * 2);
  ushort* hid   = (ushort*)alloc((size_t)MM * HH * 2);
  float*  lse   = (float*)alloc(MM * 4);
  float*  pbufM = (float*)alloc((size_t)MM * 256 * 4); // 4 MB
  float*  pbufL = (float*)alloc((size_t)MM * 256 * 4); // 4 MB
  // Gin buffers (67 MB) live in d_out-as-scratch: dead before logits GEMM writes d_out.
  float* GinE = out;
  float* GinD = out + (size_t)MM * 2048;

  k_init<<<dim3(32), dim3(256), 0, stream>>>(hbuf, tags);
  k_cvt<<<dim3(1024), dim3(256), 0, stream>>>(WihE, WihEb, 2048 * 512 / 4);
  k_cvt<<<dim3(1024), dim3(256), 0, stream>>>(WihD, WihDb, 2048 * 512 / 4);
  k_cvt<<<dim3(2048), dim3(256), 0, stream>>>(outW, outWb, VD * HH / 4);
  k_concatB<<<dim3(512), dim3(128), 0, stream>>>(We, Wd, Bc);
  k_bsum<<<dim3(2), dim3(256), 0, stream>>>(be, bd, bsum);
  k_embed<<<dim3(MM), dim3(128), 0, stream>>>(enc_in, enc_emb, xe);
  k_embed<<<dim3(MM), dim3(128), 0, stream>>>(dec_in, dec_emb, xd);
  // input projections: Gin = x @ Wih^T   [4096,512]x[2048,512]^T
  k_gemm<false, false, false, false><<<dim3(16, 32), dim3(256), 0, stream>>>(xe, WihEb, (const float*)nullptr, GinE, MM, 2048, 512, nullptr, nullptr);
  k_gemm<false, false, false, false><<<dim3(16, 32), dim3(256), 0, stream>>>(xd, WihDb, (const float*)nullptr, GinD, MM, 2048, 512, nullptr, nullptr);
  // both LSTMs (persistent, private-line tag protocol, MFMA recurrence)
  k_lstm<<<dim3(NLB), dim3(512), 0, stream>>>(GinE, GinD, WhhE, WhhD, hbuf, tags, encO, decO, Ac);
  // attention -> ctx into Ac[:, 0:512] (dec h already in Ac[:, 512:1024])
  k_attn<<<dim3(256), dim3(256), 0, stream>>>(encO, decO, Ac);
  // hidden = tanh([ctx|dec] @ [We|Wd]^T + (be+bd))   K=1024 -> bf16
  k_gemm<true, true, true, false><<<dim3(4, 32), dim3(256), 0, stream>>>(Ac, Bc, bsum, hid, MM, 512, 1024, nullptr, nullptr);
  // logits = hidden @ outW^T + out_b -> d_out (f32), + per-tile lse partials
  k_gemm<true, false, false, true><<<dim3(250, 32), dim3(256), 0, stream>>>(hid, outWb, outb, out, MM, VD, 512, pbufM, pbufL);
  // log-softmax
  k_lse2<<<dim3(1024), dim3(256), 0, stream>>>(pbufM, pbufL, lse);
  k_sub<<<dim3(MM), dim3(256), 0, stream>>>(out, lse);
}